// Round 1
// baseline (2555.955 us; speedup 1.0000x reference)
//
#include <hip/hip_runtime.h>
#include <cstddef>

// Problem constants
// N=128, L=200, LE=201, E=128, A=16 aspects, NB=2, H=2, HD=64, TEMP=0.2

// ---------------------------------------------------------------------------
// Transpose W_asp (16,128,128)[a][o][k] -> Wt (128,2048)[k][a*128+o]
__global__ void transpose_wasp(const float* __restrict__ W_asp, float* __restrict__ Wt) {
    const int ao = blockIdx.x;     // 0..2047
    const int k  = threadIdx.x;    // 0..127
    Wt[(size_t)k * 2048 + ao] = W_asp[(size_t)ao * 128 + k];
}

// ---------------------------------------------------------------------------
// Gather embeddings + valid flags.
// rows [0, 128*201): kv rows (n,l), l==200 is the appended pos_embs[:, -1].
// rows [128*201, +128*200): neg rows.
__global__ void gather_kernel(const float* __restrict__ item_emb,
                              const int* __restrict__ log_seqs,
                              const int* __restrict__ pos_seqs,
                              const int* __restrict__ neg_seqs,
                              float* __restrict__ kvx, float* __restrict__ negx,
                              float* __restrict__ validE, float* __restrict__ validL) {
    const int r = blockIdx.x;
    const int e = threadIdx.x;     // 128 threads
    const int NKV = 128 * 201;
    if (r < NKV) {
        const int n = r / 201, l = r % 201;
        float vl; int sidx;
        if (l < 200) { sidx = log_seqs[n * 200 + l]; vl = (sidx != 0) ? 1.f : 0.f; }
        else { vl = (log_seqs[n * 200 + 199] != 0) ? 1.f : 0.f; sidx = pos_seqs[n * 200 + 199]; }
        kvx[(size_t)r * 128 + e] = item_emb[(size_t)sidx * 128 + e] * vl;
        if (e == 0) validE[r] = vl;
    } else {
        const int rr = r - NKV;
        const int n = rr / 200, l = rr % 200;
        const float vl = (log_seqs[n * 200 + l] != 0) ? 1.f : 0.f;
        const int sidx = neg_seqs[n * 200 + l];
        negx[(size_t)rr * 128 + e] = item_emb[(size_t)sidx * 128 + e] * vl;
        if (e == 0) validL[rr] = vl;
    }
}

// ---------------------------------------------------------------------------
// Fused aspects kernel. 8 positions per block, 256 threads.
// Computes r[a][o] = sum_k x[k]*W_asp[a,o,k]; residual+normalize -> kv4;
// (LOSSES) cent = valid*||x - mean_a r||, ind via Gram of normalized kv4;
// gate: G[o] = sum_a kv4[a][o] * (softmax_a(kv4[a].w_a) + 1/16).
#define ARD_KK(WA, WB, CMP)                                          \
    _Pragma("unroll")                                                \
    for (int p = 0; p < 8; ++p) {                                    \
        const float xp = xv[p].CMP;                                  \
        acc[p][0] += xp * WA.x; acc[p][1] += xp * WA.y;              \
        acc[p][2] += xp * WA.z; acc[p][3] += xp * WA.w;              \
        acc[p][4] += xp * WB.x; acc[p][5] += xp * WB.y;              \
        acc[p][6] += xp * WB.z; acc[p][7] += xp * WB.w;              \
    }

template <int LOSSES>
__global__ __launch_bounds__(256, 2) void aspects_kernel(
        const float* __restrict__ X, const float* __restrict__ Wt,
        const float* __restrict__ w_weight, const float* __restrict__ validf,
        float* __restrict__ Gout, float* __restrict__ pInd, float* __restrict__ pCent,
        int nrows) {
    __shared__ float xs[8][128];
    __shared__ float rs[8][2048];
    __shared__ float shtmp[8][256];   // cent d^2 buffer, later ttl[16][16]
    __shared__ float nrm[8][16];
    __shared__ float wsm[8][16];
    __shared__ float wa[128];
    __shared__ float vld[8];
    __shared__ float centp[8];
    __shared__ float miacc[8];

    const int tid = threadIdx.x;
    const int row0 = blockIdx.x * 8;

    {   // load xs (8 rows x 128), one float4 per thread
        const int p = tid >> 5, c4 = (tid & 31) << 2;
        const int r = row0 + p;
        float4 v = make_float4(0.f, 0.f, 0.f, 0.f);
        if (r < nrows) v = *(const float4*)&X[(size_t)r * 128 + c4];
        *(float4*)&xs[p][c4] = v;
    }
    if (tid < 8) vld[tid] = (row0 + tid < nrows) ? validf[row0 + tid] : 0.f;
    if (tid >= 128) wa[tid - 128] = w_weight[tid];   // w_a = w_weight[128..256)
    __syncthreads();

    // ---- phase 1: r = x @ W^T for all 16 aspects ----
    {
        const int ao0 = tid * 8;
        float acc[8][8];
#pragma unroll
        for (int p = 0; p < 8; ++p)
#pragma unroll
            for (int j = 0; j < 8; ++j) acc[p][j] = 0.f;
        for (int k = 0; k < 128; k += 4) {
            float4 xv[8];
#pragma unroll
            for (int p = 0; p < 8; ++p) xv[p] = *(const float4*)&xs[p][k];
            float4 wA[4], wB[4];
#pragma unroll
            for (int kk = 0; kk < 4; ++kk) {
                wA[kk] = *(const float4*)&Wt[(size_t)(k + kk) * 2048 + ao0];
                wB[kk] = *(const float4*)&Wt[(size_t)(k + kk) * 2048 + ao0 + 4];
            }
            ARD_KK(wA[0], wB[0], x)
            ARD_KK(wA[1], wB[1], y)
            ARD_KK(wA[2], wB[2], z)
            ARD_KK(wA[3], wB[3], w)
        }
#pragma unroll
        for (int p = 0; p < 8; ++p) {
            *(float4*)&rs[p][ao0]     = make_float4(acc[p][0], acc[p][1], acc[p][2], acc[p][3]);
            *(float4*)&rs[p][ao0 + 4] = make_float4(acc[p][4], acc[p][5], acc[p][6], acc[p][7]);
        }
    }
    __syncthreads();

    // ---- phase 2: norms of (r + x); (LOSSES) cent d^2 ----
    if (tid < 128) {
        const int p = tid >> 4, a = tid & 15;
        const float* rp = &rs[p][a << 7];
        const float* xp = xs[p];
        const int skew = ((a << 3) + p) & 127;   // spread LDS banks
        float sacc = 0.f;
        for (int oo = 0; oo < 128; ++oo) {
            const int o = (oo + skew) & 127;
            const float v = rp[o] + xp[o];
            sacc += v * v;
        }
        nrm[p][a] = sqrtf(sacc);
    }
    if constexpr (LOSSES) {
        for (int t = tid; t < 1024; t += 256) {
            const int p = t >> 7, o = t & 127;
            float sum = 0.f;
#pragma unroll
            for (int a = 0; a < 16; ++a) sum += rs[p][(a << 7) + o];
            const float d = xs[p][o] - sum * 0.0625f;
            shtmp[p][o] = d * d;
        }
    }
    __syncthreads();
    if constexpr (LOSSES) {
        if (tid < 8) {
            float sacc = 0.f;
            for (int o = 0; o < 128; ++o) sacc += shtmp[tid][o];
            centp[tid] = sqrtf(sacc) * vld[tid];
        }
    }
    // ---- phase 3: normalize in place: kv4 = (r+x)*valid/(nrm+1e-8) ----
    for (int t = tid; t < 16384; t += 256) {
        const int p = t >> 11, ao = t & 2047, a = ao >> 7, o = ao & 127;
        const float v = rs[p][ao] + xs[p][o];
        rs[p][ao] = v * (vld[p] / (nrm[p][a] + 1e-8f));
    }
    __syncthreads();

    if constexpr (LOSSES) {
        // ---- phase 4: Gram (symmetric) scaled to norm_x, then mi ----
        for (int t = tid; t < 1088; t += 256) {   // 8 * 136 pairs (a<=b)
            const int p = t / 136;
            int rem = t - p * 136;
            int a = 0;
            while (rem >= 16 - a) { rem -= 16 - a; ++a; }
            const int b = a + rem;
            const float* ra = &rs[p][a << 7];
            const float* rb = &rs[p][b << 7];
            const int skew = t & 127;
            float d = 0.f;
            for (int oo = 0; oo < 128; ++oo) {
                const int o = (oo + skew) & 127;
                d += ra[o] * rb[o];
            }
            const float na = nrm[p][a], nb = nrm[p][b];
            const float ga = vld[p] * na / (na + 1e-8f);
            const float gb = vld[p] * nb / (nb + 1e-8f);
            const float val = d / ((ga + 1e-8f) * (gb + 1e-8f));
            shtmp[p][(a << 4) + b] = val;
            shtmp[p][(b << 4) + a] = val;
        }
        __syncthreads();
        float mired = 0.f;
        if (tid < 128) {
            const int p = tid >> 4, a = tid & 15;
            float sum = 0.f;
#pragma unroll
            for (int b = 0; b < 16; ++b) sum += expf(shtmp[p][(a << 4) + b] * 5.f);
            const float na = nrm[p][a];
            const float g = vld[p] * na / (na + 1e-8f);
            const float ts = g / (g + 1e-8f);
            const float pos_s = ts * ts;
            mired = -(pos_s * 5.f - logf(sum));
        }
#pragma unroll
        for (int m = 1; m < 16; m <<= 1) mired += __shfl_xor(mired, m, 16);
        if (tid < 128 && (tid & 15) == 0) miacc[tid >> 4] = mired * vld[tid >> 4];
    }

    // ---- phase 5: gate logits + softmax weights (+1/16) ----
    if (tid < 128) {
        const int p = tid >> 4, a = tid & 15;
        const float* rp = &rs[p][a << 7];
        const int skew = ((a << 3) + p) & 127;
        float d = 0.f;
        for (int oo = 0; oo < 128; ++oo) {
            const int o = (oo + skew) & 127;
            d += rp[o] * wa[o];
        }
        wsm[p][a] = d;
    }
    __syncthreads();
    if (tid < 8) {
        float mx = -1e30f;
#pragma unroll
        for (int a = 0; a < 16; ++a) mx = fmaxf(mx, wsm[tid][a]);
        float s = 0.f;
        float ev[16];
#pragma unroll
        for (int a = 0; a < 16; ++a) { ev[a] = expf(wsm[tid][a] - mx); s += ev[a]; }
        const float inv = 1.f / s;
#pragma unroll
        for (int a = 0; a < 16; ++a) wsm[tid][a] = ev[a] * inv + 0.0625f;
    }
    if constexpr (LOSSES) {
        if (tid == 0) {
            float si = 0.f, sc = 0.f;
            for (int p = 0; p < 8; ++p) { si += miacc[p]; sc += centp[p]; }
            pInd[blockIdx.x] = si;
            pCent[blockIdx.x] = sc;
        }
    }
    __syncthreads();

    // ---- phase 6: G = sum_a kv4[a] * wsm[a] ----
    for (int t = tid; t < 1024; t += 256) {
        const int p = t >> 7, o = t & 127;
        const int r = row0 + p;
        if (r >= nrows) continue;
        float sacc = 0.f;
#pragma unroll
        for (int a = 0; a < 16; ++a) sacc += rs[p][(a << 7) + o] * wsm[p][a];
        Gout[(size_t)r * 128 + o] = sacc;
    }
}
#undef ARD_KK

// ---------------------------------------------------------------------------
// Deterministic reduce: ind/cent partials + nvalid, write final scalars.
__global__ void reduce_kernel(const float* __restrict__ pInd, const float* __restrict__ pCent,
                              int nblk, const float* __restrict__ validE, int nve,
                              float* __restrict__ outp) {
    __shared__ float a1[256], a2[256], a3[256];
    const int tid = threadIdx.x;
    float si = 0.f, sc = 0.f, nv = 0.f;
    for (int t = tid; t < nblk; t += 256) { si += pInd[t]; sc += pCent[t]; }
    for (int t = tid; t < nve; t += 256) nv += validE[t];
    a1[tid] = si; a2[tid] = sc; a3[tid] = nv;
    __syncthreads();
    for (int s = 128; s > 0; s >>= 1) {
        if (tid < s) { a1[tid] += a1[tid + s]; a2[tid] += a2[tid + s]; a3[tid] += a3[tid + s]; }
        __syncthreads();
    }
    if (tid == 0) { outp[0] = a1[0] / a3[0]; outp[1] = a2[0] / a3[0]; }
}

// ---------------------------------------------------------------------------
// seqs = (G[:, :200] * sqrt(E) + pos_emb[0:200]) * validL
__global__ void seqs_init(const float* __restrict__ G, const float* __restrict__ pos_emb,
                          const float* __restrict__ validL, float* __restrict__ seqs) {
    const int idx = blockIdx.x * 256 + threadIdx.x;   // over 25600*128
    const int e = idx & 127;
    const int nl = idx >> 7;
    const int l = nl % 200, n = nl / 200;
    const float v = G[((size_t)n * 201 + l) * 128 + e] * 11.313708498984761f + pos_emb[l * 128 + e];
    seqs[idx] = v * validL[nl];
}

// ---------------------------------------------------------------------------
// Generic 128-col GEMM: C[m,o] = sum_k X[m,k]*W[o,k] + bias[o] (+res)(relu)(*mask)
template <int RELU, int HASRES, int HASMASK>
__global__ __launch_bounds__(256, 4) void gemm128_kernel(
        const float* __restrict__ X, const float* __restrict__ W,
        const float* __restrict__ bias, const float* __restrict__ res,
        const float* __restrict__ mask, float* __restrict__ C, int M) {
    __shared__ float Xs[64][132];
    const int row0 = blockIdx.x * 64;
    const int tid = threadIdx.x;
    for (int t = tid; t < 2048; t += 256) {   // 64 rows * 32 float4
        const int r = t >> 5, c4 = (t & 31) << 2;
        float4 v = make_float4(0.f, 0.f, 0.f, 0.f);
        if (row0 + r < M) v = *(const float4*)&X[(size_t)(row0 + r) * 128 + c4];
        *(float4*)&Xs[r][c4] = v;
    }
    __syncthreads();
    const int tx = tid & 15, ty = tid >> 4;
    const int r0 = ty * 4, c0 = tx * 8;
    float acc[4][8];
#pragma unroll
    for (int i = 0; i < 4; ++i)
#pragma unroll
        for (int j = 0; j < 8; ++j) acc[i][j] = 0.f;
    for (int k = 0; k < 128; k += 4) {
        float4 xv[4];
#pragma unroll
        for (int i = 0; i < 4; ++i) xv[i] = *(const float4*)&Xs[r0 + i][k];
#pragma unroll
        for (int j = 0; j < 8; ++j) {
            const float4 wv = *(const float4*)&W[(size_t)(c0 + j) * 128 + k];
#pragma unroll
            for (int i = 0; i < 4; ++i)
                acc[i][j] += xv[i].x * wv.x + xv[i].y * wv.y + xv[i].z * wv.z + xv[i].w * wv.w;
        }
    }
#pragma unroll
    for (int i = 0; i < 4; ++i) {
        const int r = row0 + r0 + i;
        if (r >= M) continue;
        float mk = 1.f;
        if (HASMASK) mk = mask[r];
#pragma unroll
        for (int j = 0; j < 8; ++j) {
            float v = acc[i][j] + bias[c0 + j];
            if (HASRES) v += res[(size_t)r * 128 + c0 + j];
            if (RELU) v = fmaxf(v, 0.f);
            if (HASMASK) v *= mk;
            C[(size_t)r * 128 + c0 + j] = v;
        }
    }
}

// ---------------------------------------------------------------------------
// LayerNorm over last dim (128), eps=1e-8. One wave per row.
__global__ __launch_bounds__(256) void ln_kernel(const float* __restrict__ X,
                                                 const float* __restrict__ g,
                                                 const float* __restrict__ b,
                                                 float* __restrict__ Y, int M) {
    const int row = blockIdx.x * 4 + (threadIdx.x >> 6);
    const int lane = threadIdx.x & 63;
    if (row >= M) return;
    const float2 x = *(const float2*)&X[(size_t)row * 128 + lane * 2];
    float s = x.x + x.y, sq = x.x * x.x + x.y * x.y;
#pragma unroll
    for (int m = 1; m < 64; m <<= 1) { s += __shfl_xor(s, m, 64); sq += __shfl_xor(sq, m, 64); }
    const float mean = s * 0.0078125f;
    const float var = fmaxf(sq * 0.0078125f - mean * mean, 0.f);
    const float inv = rsqrtf(var + 1e-8f);
    const float2 gg = *(const float2*)&g[lane * 2];
    const float2 bb = *(const float2*)&b[lane * 2];
    float2 y;
    y.x = (x.x - mean) * inv * gg.x + bb.x;
    y.y = (x.y - mean) * inv * gg.y + bb.y;
    *(float2*)&Y[(size_t)row * 128 + lane * 2] = y;
}

// ---------------------------------------------------------------------------
// Causal attention, one block per (n, head). H=2, HD=64, L=200.
__global__ __launch_bounds__(256) void attn_kernel(const float* __restrict__ qp,
                                                   const float* __restrict__ kp,
                                                   const float* __restrict__ vp,
                                                   float* __restrict__ outp) {
    __shared__ float Ks[200][65];
    __shared__ float Vs[200][65];
    __shared__ float qrow[64];
    __shared__ float prow[200];
    __shared__ float red[8];
    __shared__ float opart[4][64];

    const int tid = threadIdx.x;
    const int n = blockIdx.x >> 1, h = blockIdx.x & 1;
    const size_t base = ((size_t)n * 200) * 128 + (size_t)h * 64;
    for (int t = tid; t < 200 * 64; t += 256) {
        const int j = t >> 6, e = t & 63;
        Ks[j][e] = kp[base + (size_t)j * 128 + e];
        Vs[j][e] = vp[base + (size_t)j * 128 + e];
    }
    __syncthreads();
    const int lane = tid & 63, wv = tid >> 6;
    for (int l = 0; l < 200; ++l) {
        if (tid < 64) qrow[tid] = qp[base + (size_t)l * 128 + tid];
        __syncthreads();
        float s = -3.0e38f;
        if (tid <= l) {
            float acc = 0.f;
#pragma unroll 16
            for (int e = 0; e < 64; ++e) acc += qrow[e] * Ks[tid][e];
            s = acc * 0.125f;
        }
        float m = s;
#pragma unroll
        for (int msk = 1; msk < 64; msk <<= 1) m = fmaxf(m, __shfl_xor(m, msk, 64));
        if (lane == 0) red[wv] = m;
        __syncthreads();
        m = fmaxf(fmaxf(red[0], red[1]), fmaxf(red[2], red[3]));
        const float p = (tid <= l) ? expf(s - m) : 0.f;
        float sum = p;
#pragma unroll
        for (int msk = 1; msk < 64; msk <<= 1) sum += __shfl_xor(sum, msk, 64);
        if (lane == 0) red[4 + wv] = sum;
        __syncthreads();
        const float denom = red[4] + red[5] + red[6] + red[7];
        if (tid < 200) prow[tid] = p / denom;
        __syncthreads();
        float acc = 0.f;
        for (int j = wv; j <= l; j += 4) acc += prow[j] * Vs[j][lane];
        opart[wv][lane] = acc;
        __syncthreads();
        if (tid < 64)
            outp[base + (size_t)l * 128 + tid] =
                opart[0][tid] + opart[1][tid] + opart[2][tid] + opart[3][tid];
        __syncthreads();
    }
}

// ---------------------------------------------------------------------------
// pos_logits[row] = validL[row] * <lf[row], G[n, j+1]>;  neg_logits = <lf, negt>
__global__ __launch_bounds__(256) void logits_kernel(const float* __restrict__ lf,
                                                     const float* __restrict__ G,
                                                     const float* __restrict__ negt,
                                                     const float* __restrict__ validL,
                                                     float* __restrict__ outp) {
    const int row = blockIdx.x * 4 + (threadIdx.x >> 6);
    const int lane = threadIdx.x & 63;
    if (row >= 25600) return;
    const int n = row / 200, j = row % 200;
    const float2 x  = *(const float2*)&lf[(size_t)row * 128 + lane * 2];
    const float2 g2 = *(const float2*)&G[((size_t)n * 201 + j + 1) * 128 + lane * 2];
    const float2 t2 = *(const float2*)&negt[(size_t)row * 128 + lane * 2];
    float sp = x.x * g2.x + x.y * g2.y;
    float sn = x.x * t2.x + x.y * t2.y;
#pragma unroll
    for (int m = 1; m < 64; m <<= 1) { sp += __shfl_xor(sp, m, 64); sn += __shfl_xor(sn, m, 64); }
    if (lane == 0) { outp[row] = sp * validL[row]; outp[25600 + row] = sn; }
}

// ---------------------------------------------------------------------------
extern "C" void kernel_launch(void* const* d_in, const int* in_sizes, int n_in,
                              void* d_out, int out_size, void* d_ws, size_t ws_size,
                              hipStream_t stream) {
    (void)in_sizes; (void)n_in; (void)out_size; (void)ws_size;
    const float* item_emb = (const float*)d_in[0];
    const float* pos_emb  = (const float*)d_in[1];
    const float* W_asp    = (const float*)d_in[2];
    const float* w_weight = (const float*)d_in[3];
    // d_in[4] w_bias: cancels in aspect softmax (shift invariance)
    const float* attn_g = (const float*)d_in[5];
    const float* attn_b = (const float*)d_in[6];
    const float* inW    = (const float*)d_in[7];
    const float* inB    = (const float*)d_in[8];
    const float* outW   = (const float*)d_in[9];
    const float* outB   = (const float*)d_in[10];
    const float* fwd_g  = (const float*)d_in[11];
    const float* fwd_b  = (const float*)d_in[12];
    const float* c1w    = (const float*)d_in[13];
    const float* c1b    = (const float*)d_in[14];
    const float* c2w    = (const float*)d_in[15];
    const float* c2b    = (const float*)d_in[16];
    const float* last_g = (const float*)d_in[17];
    const float* last_b = (const float*)d_in[18];
    const int* log_seqs = (const int*)d_in[20];
    const int* pos_seqs = (const int*)d_in[21];
    const int* neg_seqs = (const int*)d_in[22];

    float* ws = (float*)d_ws;
    const size_t S = (size_t)128 * 201 * 128;  // one (N, 201, 128) slot
    float* kvx   = ws;           float* qp = kvx;   // reuse after aspects<1>
    float* negx  = ws + S;       float* kp = negx;  // reuse after aspects<0>
    float* G     = ws + 2 * S;
    float* negt  = ws + 3 * S;
    float* seqs  = ws + 4 * S;
    float* Qn    = ws + 5 * S;   // also F and log_feats
    float* vp    = ws + 6 * S;
    float* attno = ws + 7 * S;
    float* Wt     = ws + 8 * S;
    float* validE = Wt + (size_t)2048 * 128;
    float* validL = validE + 128 * 201;
    float* pInd   = validL + 128 * 200;
    float* pCent  = pInd + 3216;
    float* outF   = (float*)d_out;

    const int M = 128 * 200;  // 25600

    transpose_wasp<<<dim3(2048), dim3(128), 0, stream>>>(W_asp, Wt);
    gather_kernel<<<dim3(128 * 201 + 128 * 200), dim3(128), 0, stream>>>(
        item_emb, log_seqs, pos_seqs, neg_seqs, kvx, negx, validE, validL);
    aspects_kernel<1><<<dim3(3216), dim3(256), 0, stream>>>(
        kvx, Wt, w_weight, validE, G, pInd, pCent, 128 * 201);
    aspects_kernel<0><<<dim3(3200), dim3(256), 0, stream>>>(
        negx, Wt, w_weight, validL, negt, nullptr, nullptr, 128 * 200);
    reduce_kernel<<<dim3(1), dim3(256), 0, stream>>>(
        pInd, pCent, 3216, validE, 128 * 201, outF + 51200);
    seqs_init<<<dim3(12800), dim3(256), 0, stream>>>(G, pos_emb, validL, seqs);

    for (int i = 0; i < 2; ++i) {
        const float* Wq = inW + (size_t)i * 384 * 128;
        const float* Wk = Wq + 128 * 128;
        const float* Wv = Wk + 128 * 128;
        const float* bq = inB + (size_t)i * 384;
        const float* bk = bq + 128;
        const float* bv = bk + 128;
        ln_kernel<<<dim3(6400), dim3(256), 0, stream>>>(seqs, attn_g + i * 128, attn_b + i * 128, Qn, M);
        gemm128_kernel<0, 0, 0><<<dim3(400), dim3(256), 0, stream>>>(Qn,   Wq, bq, nullptr, nullptr, qp, M);
        gemm128_kernel<0, 0, 0><<<dim3(400), dim3(256), 0, stream>>>(seqs, Wk, bk, nullptr, nullptr, kp, M);
        gemm128_kernel<0, 0, 0><<<dim3(400), dim3(256), 0, stream>>>(seqs, Wv, bv, nullptr, nullptr, vp, M);
        attn_kernel<<<dim3(256), dim3(256), 0, stream>>>(qp, kp, vp, attno);
        gemm128_kernel<0, 1, 0><<<dim3(400), dim3(256), 0, stream>>>(
            attno, outW + (size_t)i * 128 * 128, outB + i * 128, Qn, nullptr, seqs, M);
        ln_kernel<<<dim3(6400), dim3(256), 0, stream>>>(seqs, fwd_g + i * 128, fwd_b + i * 128, Qn, M);
        gemm128_kernel<1, 0, 0><<<dim3(400), dim3(256), 0, stream>>>(
            Qn, c1w + (size_t)i * 128 * 128, c1b + i * 128, nullptr, nullptr, qp, M);
        gemm128_kernel<0, 1, 1><<<dim3(400), dim3(256), 0, stream>>>(
            qp, c2w + (size_t)i * 128 * 128, c2b + i * 128, Qn, validL, seqs, M);
    }
    ln_kernel<<<dim3(6400), dim3(256), 0, stream>>>(seqs, last_g, last_b, Qn, M);
    logits_kernel<<<dim3(6400), dim3(256), 0, stream>>>(Qn, G, negt, validL, outF);
}

// Round 2
// 1688.614 us; speedup vs baseline: 1.5136x; 1.5136x over previous
//
#include <hip/hip_runtime.h>
#include <cstddef>

// Problem constants
// N=128, L=200, LE=201, E=128, A=16 aspects, NB=2, H=2, HD=64, TEMP=0.2

// ---------------------------------------------------------------------------
// Transpose W_asp (16,128,128)[a][o][k] -> Wt (128,2048)[k][a*128+o]
__global__ void transpose_wasp(const float* __restrict__ W_asp, float* __restrict__ Wt) {
    const int ao = blockIdx.x;     // 0..2047
    const int k  = threadIdx.x;    // 0..127
    Wt[(size_t)k * 2048 + ao] = W_asp[(size_t)ao * 128 + k];
}

// ---------------------------------------------------------------------------
// Gather embeddings + valid flags.
__global__ void gather_kernel(const float* __restrict__ item_emb,
                              const int* __restrict__ log_seqs,
                              const int* __restrict__ pos_seqs,
                              const int* __restrict__ neg_seqs,
                              float* __restrict__ kvx, float* __restrict__ negx,
                              float* __restrict__ validE, float* __restrict__ validL) {
    const int r = blockIdx.x;
    const int e = threadIdx.x;     // 128 threads
    const int NKV = 128 * 201;
    if (r < NKV) {
        const int n = r / 201, l = r % 201;
        float vl; int sidx;
        if (l < 200) { sidx = log_seqs[n * 200 + l]; vl = (sidx != 0) ? 1.f : 0.f; }
        else { vl = (log_seqs[n * 200 + 199] != 0) ? 1.f : 0.f; sidx = pos_seqs[n * 200 + 199]; }
        kvx[(size_t)r * 128 + e] = item_emb[(size_t)sidx * 128 + e] * vl;
        if (e == 0) validE[r] = vl;
    } else {
        const int rr = r - NKV;
        const int n = rr / 200, l = rr % 200;
        const float vl = (log_seqs[n * 200 + l] != 0) ? 1.f : 0.f;
        const int sidx = neg_seqs[n * 200 + l];
        negx[(size_t)rr * 128 + e] = item_emb[(size_t)sidx * 128 + e] * vl;
        if (e == 0) validL[rr] = vl;
    }
}

// ---------------------------------------------------------------------------
// Fused aspects kernel. 8 positions per block, 256 threads.
#define ARD_KK(WA, WB, CMP)                                          \
    _Pragma("unroll")                                                \
    for (int p = 0; p < 8; ++p) {                                    \
        const float xp = xv[p].CMP;                                  \
        acc[p][0] += xp * WA.x; acc[p][1] += xp * WA.y;              \
        acc[p][2] += xp * WA.z; acc[p][3] += xp * WA.w;              \
        acc[p][4] += xp * WB.x; acc[p][5] += xp * WB.y;              \
        acc[p][6] += xp * WB.z; acc[p][7] += xp * WB.w;              \
    }

template <int LOSSES>
__global__ __launch_bounds__(256, 2) void aspects_kernel(
        const float* __restrict__ X, const float* __restrict__ Wt,
        const float* __restrict__ w_weight, const float* __restrict__ validf,
        float* __restrict__ Gout, float* __restrict__ pInd, float* __restrict__ pCent,
        int nrows) {
    __shared__ float xs[8][128];
    __shared__ float rs[8][2048];
    __shared__ float shtmp[8][256];   // cent d^2 buffer, later ttl[16][16]
    __shared__ float nrm[8][16];
    __shared__ float wsm[8][16];
    __shared__ float wa[128];
    __shared__ float vld[8];
    __shared__ float centp[8];
    __shared__ float miacc[8];

    const int tid = threadIdx.x;
    const int row0 = blockIdx.x * 8;

    {   // load xs (8 rows x 128), one float4 per thread
        const int p = tid >> 5, c4 = (tid & 31) << 2;
        const int r = row0 + p;
        float4 v = make_float4(0.f, 0.f, 0.f, 0.f);
        if (r < nrows) v = *(const float4*)&X[(size_t)r * 128 + c4];
        *(float4*)&xs[p][c4] = v;
    }
    if (tid < 8) vld[tid] = (row0 + tid < nrows) ? validf[row0 + tid] : 0.f;
    if (tid >= 128) wa[tid - 128] = w_weight[tid];   // w_a = w_weight[128..256)
    __syncthreads();

    // ---- phase 1: r = x @ W^T for all 16 aspects ----
    {
        const int ao0 = tid * 8;
        float acc[8][8];
#pragma unroll
        for (int p = 0; p < 8; ++p)
#pragma unroll
            for (int j = 0; j < 8; ++j) acc[p][j] = 0.f;
        for (int k = 0; k < 128; k += 4) {
            float4 xv[8];
#pragma unroll
            for (int p = 0; p < 8; ++p) xv[p] = *(const float4*)&xs[p][k];
            float4 wA[4], wB[4];
#pragma unroll
            for (int kk = 0; kk < 4; ++kk) {
                wA[kk] = *(const float4*)&Wt[(size_t)(k + kk) * 2048 + ao0];
                wB[kk] = *(const float4*)&Wt[(size_t)(k + kk) * 2048 + ao0 + 4];
            }
            ARD_KK(wA[0], wB[0], x)
            ARD_KK(wA[1], wB[1], y)
            ARD_KK(wA[2], wB[2], z)
            ARD_KK(wA[3], wB[3], w)
        }
#pragma unroll
        for (int p = 0; p < 8; ++p) {
            *(float4*)&rs[p][ao0]     = make_float4(acc[p][0], acc[p][1], acc[p][2], acc[p][3]);
            *(float4*)&rs[p][ao0 + 4] = make_float4(acc[p][4], acc[p][5], acc[p][6], acc[p][7]);
        }
    }
    __syncthreads();

    // ---- phase 2: norms of (r + x); (LOSSES) cent d^2 ----
    if (tid < 128) {
        const int p = tid >> 4, a = tid & 15;
        const float* rp = &rs[p][a << 7];
        const float* xp = xs[p];
        const int skew = ((a << 3) + p) & 127;   // spread LDS banks
        float sacc = 0.f;
        for (int oo = 0; oo < 128; ++oo) {
            const int o = (oo + skew) & 127;
            const float v = rp[o] + xp[o];
            sacc += v * v;
        }
        nrm[p][a] = sqrtf(sacc);
    }
    if constexpr (LOSSES) {
        for (int t = tid; t < 1024; t += 256) {
            const int p = t >> 7, o = t & 127;
            float sum = 0.f;
#pragma unroll
            for (int a = 0; a < 16; ++a) sum += rs[p][(a << 7) + o];
            const float d = xs[p][o] - sum * 0.0625f;
            shtmp[p][o] = d * d;
        }
    }
    __syncthreads();
    if constexpr (LOSSES) {
        if (tid < 8) {
            float sacc = 0.f;
            for (int o = 0; o < 128; ++o) sacc += shtmp[tid][o];
            centp[tid] = sqrtf(sacc) * vld[tid];
        }
    }
    // ---- phase 3: normalize in place: kv4 = (r+x)*valid/(nrm+1e-8) ----
    for (int t = tid; t < 16384; t += 256) {
        const int p = t >> 11, ao = t & 2047, a = ao >> 7, o = ao & 127;
        const float v = rs[p][ao] + xs[p][o];
        rs[p][ao] = v * (vld[p] / (nrm[p][a] + 1e-8f));
    }
    __syncthreads();

    if constexpr (LOSSES) {
        // ---- phase 4: Gram (symmetric) scaled to norm_x, then mi ----
        for (int t = tid; t < 1088; t += 256) {   // 8 * 136 pairs (a<=b)
            const int p = t / 136;
            int rem = t - p * 136;
            int a = 0;
            while (rem >= 16 - a) { rem -= 16 - a; ++a; }
            const int b = a + rem;
            const float* ra = &rs[p][a << 7];
            const float* rb = &rs[p][b << 7];
            const int skew = t & 127;
            float d = 0.f;
            for (int oo = 0; oo < 128; ++oo) {
                const int o = (oo + skew) & 127;
                d += ra[o] * rb[o];
            }
            const float na = nrm[p][a], nb = nrm[p][b];
            const float ga = vld[p] * na / (na + 1e-8f);
            const float gb = vld[p] * nb / (nb + 1e-8f);
            const float val = d / ((ga + 1e-8f) * (gb + 1e-8f));
            shtmp[p][(a << 4) + b] = val;
            shtmp[p][(b << 4) + a] = val;
        }
        __syncthreads();
        float mired = 0.f;
        if (tid < 128) {
            const int p = tid >> 4, a = tid & 15;
            float sum = 0.f;
#pragma unroll
            for (int b = 0; b < 16; ++b) sum += expf(shtmp[p][(a << 4) + b] * 5.f);
            const float na = nrm[p][a];
            const float g = vld[p] * na / (na + 1e-8f);
            const float ts = g / (g + 1e-8f);
            const float pos_s = ts * ts;
            mired = -(pos_s * 5.f - logf(sum));
        }
#pragma unroll
        for (int m = 1; m < 16; m <<= 1) mired += __shfl_xor(mired, m, 16);
        if (tid < 128 && (tid & 15) == 0) miacc[tid >> 4] = mired * vld[tid >> 4];
    }

    // ---- phase 5: gate logits + softmax weights (+1/16) ----
    if (tid < 128) {
        const int p = tid >> 4, a = tid & 15;
        const float* rp = &rs[p][a << 7];
        const int skew = ((a << 3) + p) & 127;
        float d = 0.f;
        for (int oo = 0; oo < 128; ++oo) {
            const int o = (oo + skew) & 127;
            d += rp[o] * wa[o];
        }
        wsm[p][a] = d;
    }
    __syncthreads();
    if (tid < 8) {
        float mx = -1e30f;
#pragma unroll
        for (int a = 0; a < 16; ++a) mx = fmaxf(mx, wsm[tid][a]);
        float s = 0.f;
        float ev[16];
#pragma unroll
        for (int a = 0; a < 16; ++a) { ev[a] = expf(wsm[tid][a] - mx); s += ev[a]; }
        const float inv = 1.f / s;
#pragma unroll
        for (int a = 0; a < 16; ++a) wsm[tid][a] = ev[a] * inv + 0.0625f;
    }
    if constexpr (LOSSES) {
        if (tid == 0) {
            float si = 0.f, sc = 0.f;
            for (int p = 0; p < 8; ++p) { si += miacc[p]; sc += centp[p]; }
            pInd[blockIdx.x] = si;
            pCent[blockIdx.x] = sc;
        }
    }
    __syncthreads();

    // ---- phase 6: G = sum_a kv4[a] * wsm[a] ----
    for (int t = tid; t < 1024; t += 256) {
        const int p = t >> 7, o = t & 127;
        const int r = row0 + p;
        if (r >= nrows) continue;
        float sacc = 0.f;
#pragma unroll
        for (int a = 0; a < 16; ++a) sacc += rs[p][(a << 7) + o] * wsm[p][a];
        Gout[(size_t)r * 128 + o] = sacc;
    }
}
#undef ARD_KK

// ---------------------------------------------------------------------------
// Deterministic reduce: ind/cent partials + nvalid, write final scalars.
__global__ void reduce_kernel(const float* __restrict__ pInd, const float* __restrict__ pCent,
                              int nblk, const float* __restrict__ validE, int nve,
                              float* __restrict__ outp) {
    __shared__ float a1[256], a2[256], a3[256];
    const int tid = threadIdx.x;
    float si = 0.f, sc = 0.f, nv = 0.f;
    for (int t = tid; t < nblk; t += 256) { si += pInd[t]; sc += pCent[t]; }
    for (int t = tid; t < nve; t += 256) nv += validE[t];
    a1[tid] = si; a2[tid] = sc; a3[tid] = nv;
    __syncthreads();
    for (int s = 128; s > 0; s >>= 1) {
        if (tid < s) { a1[tid] += a1[tid + s]; a2[tid] += a2[tid + s]; a3[tid] += a3[tid + s]; }
        __syncthreads();
    }
    if (tid == 0) { outp[0] = a1[0] / a3[0]; outp[1] = a2[0] / a3[0]; }
}

// ---------------------------------------------------------------------------
// seqs = (G[:, :200] * sqrt(E) + pos_emb[0:200]) * validL
__global__ void seqs_init(const float* __restrict__ G, const float* __restrict__ pos_emb,
                          const float* __restrict__ validL, float* __restrict__ seqs) {
    const int idx = blockIdx.x * 256 + threadIdx.x;   // over 25600*128
    const int e = idx & 127;
    const int nl = idx >> 7;
    const int l = nl % 200, n = nl / 200;
    const float v = G[((size_t)n * 201 + l) * 128 + e] * 11.313708498984761f + pos_emb[l * 128 + e];
    seqs[idx] = v * validL[nl];
}

// ---------------------------------------------------------------------------
// Generic 128-col GEMM: C[m,o] = sum_k X[m,k]*W[o,k] + bias[o] (+res)(relu)(*mask)
template <int RELU, int HASRES, int HASMASK>
__global__ __launch_bounds__(256, 4) void gemm128_kernel(
        const float* __restrict__ X, const float* __restrict__ W,
        const float* __restrict__ bias, const float* __restrict__ res,
        const float* __restrict__ mask, float* __restrict__ C, int M) {
    __shared__ float Xs[64][132];
    const int row0 = blockIdx.x * 64;
    const int tid = threadIdx.x;
    for (int t = tid; t < 2048; t += 256) {   // 64 rows * 32 float4
        const int r = t >> 5, c4 = (t & 31) << 2;
        float4 v = make_float4(0.f, 0.f, 0.f, 0.f);
        if (row0 + r < M) v = *(const float4*)&X[(size_t)(row0 + r) * 128 + c4];
        *(float4*)&Xs[r][c4] = v;
    }
    __syncthreads();
    const int tx = tid & 15, ty = tid >> 4;
    const int r0 = ty * 4, c0 = tx * 8;
    float acc[4][8];
#pragma unroll
    for (int i = 0; i < 4; ++i)
#pragma unroll
        for (int j = 0; j < 8; ++j) acc[i][j] = 0.f;
    for (int k = 0; k < 128; k += 4) {
        float4 xv[4];
#pragma unroll
        for (int i = 0; i < 4; ++i) xv[i] = *(const float4*)&Xs[r0 + i][k];
#pragma unroll
        for (int j = 0; j < 8; ++j) {
            const float4 wv = *(const float4*)&W[(size_t)(c0 + j) * 128 + k];
#pragma unroll
            for (int i = 0; i < 4; ++i)
                acc[i][j] += xv[i].x * wv.x + xv[i].y * wv.y + xv[i].z * wv.z + xv[i].w * wv.w;
        }
    }
#pragma unroll
    for (int i = 0; i < 4; ++i) {
        const int r = row0 + r0 + i;
        if (r >= M) continue;
        float mk = 1.f;
        if (HASMASK) mk = mask[r];
#pragma unroll
        for (int j = 0; j < 8; ++j) {
            float v = acc[i][j] + bias[c0 + j];
            if (HASRES) v += res[(size_t)r * 128 + c0 + j];
            if (RELU) v = fmaxf(v, 0.f);
            if (HASMASK) v *= mk;
            C[(size_t)r * 128 + c0 + j] = v;
        }
    }
}

// ---------------------------------------------------------------------------
// LayerNorm over last dim (128), eps=1e-8. One wave per row.
__global__ __launch_bounds__(256) void ln_kernel(const float* __restrict__ X,
                                                 const float* __restrict__ g,
                                                 const float* __restrict__ b,
                                                 float* __restrict__ Y, int M) {
    const int row = blockIdx.x * 4 + (threadIdx.x >> 6);
    const int lane = threadIdx.x & 63;
    if (row >= M) return;
    const float2 x = *(const float2*)&X[(size_t)row * 128 + lane * 2];
    float s = x.x + x.y, sq = x.x * x.x + x.y * x.y;
#pragma unroll
    for (int m = 1; m < 64; m <<= 1) { s += __shfl_xor(s, m, 64); sq += __shfl_xor(sq, m, 64); }
    const float mean = s * 0.0078125f;
    const float var = fmaxf(sq * 0.0078125f - mean * mean, 0.f);
    const float inv = rsqrtf(var + 1e-8f);
    const float2 gg = *(const float2*)&g[lane * 2];
    const float2 bb = *(const float2*)&b[lane * 2];
    float2 y;
    y.x = (x.x - mean) * inv * gg.x + bb.x;
    y.y = (x.y - mean) * inv * gg.y + bb.y;
    *(float2*)&Y[(size_t)row * 128 + lane * 2] = y;
}

// ---------------------------------------------------------------------------
// Flash-style causal attention: one block per (n,h), one QUERY PER THREAD.
// q-row and o-accumulator live in registers (statically indexed); K/V tiles
// of 32 rows staged in LDS; all lanes read the same K/V row -> LDS broadcast.
__global__ __launch_bounds__(256) void attn_kernel(const float* __restrict__ qp,
                                                   const float* __restrict__ kp,
                                                   const float* __restrict__ vp,
                                                   float* __restrict__ outp) {
    constexpr int TJ = 32;
    __shared__ float Ks[TJ][64];
    __shared__ float Vs[TJ][64];
    const int tid = threadIdx.x;
    const int n = blockIdx.x >> 1, h = blockIdx.x & 1;
    const size_t base = ((size_t)n * 200) * 128 + (size_t)h * 64;
    const int q = tid;                    // query row owned by this thread
    float qv[64], ov[64];
    float mrun = -3.0e38f, lrun = 0.f;
    if (q < 200) {
#pragma unroll
        for (int e = 0; e < 64; e += 4)
            *(float4*)&qv[e] = *(const float4*)&qp[base + (size_t)q * 128 + e];
    }
#pragma unroll
    for (int e = 0; e < 64; ++e) ov[e] = 0.f;

    for (int jt = 0; jt < 200; jt += TJ) {
        const int nj = min(TJ, 200 - jt);
        // stage K/V tile (zero-fill tail rows so masked lanes never hit NaN)
        for (int t = tid; t < TJ * 16; t += 256) {
            const int j = t >> 4, c4 = (t & 15) << 2;
            float4 kvt = make_float4(0.f, 0.f, 0.f, 0.f), vvt = kvt;
            if (j < nj) {
                kvt = *(const float4*)&kp[base + (size_t)(jt + j) * 128 + c4];
                vvt = *(const float4*)&vp[base + (size_t)(jt + j) * 128 + c4];
            }
            *(float4*)&Ks[j][c4] = kvt;
            *(float4*)&Vs[j][c4] = vvt;
        }
        __syncthreads();
        if (q < 200 && jt <= q) {
            const int jmax = min(nj, q - jt + 1);
            for (int j0 = 0; j0 < jmax; j0 += 8) {
                const int jn = jmax - j0;       // >=1
                float s[8];
                float cmax = mrun;
#pragma unroll
                for (int j = 0; j < 8; ++j) {
                    float a0 = 0.f, a1 = 0.f, a2 = 0.f, a3 = 0.f;
#pragma unroll
                    for (int e = 0; e < 64; e += 4) {
                        const float4 k4 = *(const float4*)&Ks[j0 + j][e];
                        a0 += qv[e]     * k4.x;
                        a1 += qv[e + 1] * k4.y;
                        a2 += qv[e + 2] * k4.z;
                        a3 += qv[e + 3] * k4.w;
                    }
                    s[j] = (j < jn) ? ((a0 + a1) + (a2 + a3)) * 0.125f : -3.0e38f;
                    cmax = fmaxf(cmax, s[j]);
                }
                if (cmax > mrun) {
                    const float c = __expf(mrun - cmax);
                    lrun *= c;
#pragma unroll
                    for (int e = 0; e < 64; ++e) ov[e] *= c;
                    mrun = cmax;
                }
#pragma unroll
                for (int j = 0; j < 8; ++j) {
                    const float p = __expf(s[j] - mrun);   // 0 for masked j
                    lrun += p;
#pragma unroll
                    for (int e = 0; e < 64; e += 4) {
                        const float4 v4 = *(const float4*)&Vs[j0 + j][e];
                        ov[e]     += p * v4.x;
                        ov[e + 1] += p * v4.y;
                        ov[e + 2] += p * v4.z;
                        ov[e + 3] += p * v4.w;
                    }
                }
            }
        }
        __syncthreads();
    }
    if (q < 200) {
        const float inv = 1.f / lrun;
#pragma unroll
        for (int e = 0; e < 64; e += 4) {
            const float4 o4 = make_float4(ov[e] * inv, ov[e + 1] * inv,
                                          ov[e + 2] * inv, ov[e + 3] * inv);
            *(float4*)&outp[base + (size_t)q * 128 + e] = o4;
        }
    }
}

// ---------------------------------------------------------------------------
// pos_logits[row] = validL[row] * <lf[row], G[n, j+1]>;  neg_logits = <lf, negt>
__global__ __launch_bounds__(256) void logits_kernel(const float* __restrict__ lf,
                                                     const float* __restrict__ G,
                                                     const float* __restrict__ negt,
                                                     const float* __restrict__ validL,
                                                     float* __restrict__ outp) {
    const int row = blockIdx.x * 4 + (threadIdx.x >> 6);
    const int lane = threadIdx.x & 63;
    if (row >= 25600) return;
    const int n = row / 200, j = row % 200;
    const float2 x  = *(const float2*)&lf[(size_t)row * 128 + lane * 2];
    const float2 g2 = *(const float2*)&G[((size_t)n * 201 + j + 1) * 128 + lane * 2];
    const float2 t2 = *(const float2*)&negt[(size_t)row * 128 + lane * 2];
    float sp = x.x * g2.x + x.y * g2.y;
    float sn = x.x * t2.x + x.y * t2.y;
#pragma unroll
    for (int m = 1; m < 64; m <<= 1) { sp += __shfl_xor(sp, m, 64); sn += __shfl_xor(sn, m, 64); }
    if (lane == 0) { outp[row] = sp * validL[row]; outp[25600 + row] = sn; }
}

// ---------------------------------------------------------------------------
extern "C" void kernel_launch(void* const* d_in, const int* in_sizes, int n_in,
                              void* d_out, int out_size, void* d_ws, size_t ws_size,
                              hipStream_t stream) {
    (void)in_sizes; (void)n_in; (void)out_size; (void)ws_size;
    const float* item_emb = (const float*)d_in[0];
    const float* pos_emb  = (const float*)d_in[1];
    const float* W_asp    = (const float*)d_in[2];
    const float* w_weight = (const float*)d_in[3];
    // d_in[4] w_bias: cancels in aspect softmax (shift invariance)
    const float* attn_g = (const float*)d_in[5];
    const float* attn_b = (const float*)d_in[6];
    const float* inW    = (const float*)d_in[7];
    const float* inB    = (const float*)d_in[8];
    const float* outW   = (const float*)d_in[9];
    const float* outB   = (const float*)d_in[10];
    const float* fwd_g  = (const float*)d_in[11];
    const float* fwd_b  = (const float*)d_in[12];
    const float* c1w    = (const float*)d_in[13];
    const float* c1b    = (const float*)d_in[14];
    const float* c2w    = (const float*)d_in[15];
    const float* c2b    = (const float*)d_in[16];
    const float* last_g = (const float*)d_in[17];
    const float* last_b = (const float*)d_in[18];
    const int* log_seqs = (const int*)d_in[20];
    const int* pos_seqs = (const int*)d_in[21];
    const int* neg_seqs = (const int*)d_in[22];

    float* ws = (float*)d_ws;
    const size_t S = (size_t)128 * 201 * 128;  // one (N, 201, 128) slot
    float* kvx   = ws;           float* qp = kvx;   // reuse after aspects<1>
    float* negx  = ws + S;       float* kp = negx;  // reuse after aspects<0>
    float* G     = ws + 2 * S;
    float* negt  = ws + 3 * S;
    float* seqs  = ws + 4 * S;
    float* Qn    = ws + 5 * S;   // also F and log_feats
    float* vp    = ws + 6 * S;
    float* attno = ws + 7 * S;
    float* Wt     = ws + 8 * S;
    float* validE = Wt + (size_t)2048 * 128;
    float* validL = validE + 128 * 201;
    float* pInd   = validL + 128 * 200;
    float* pCent  = pInd + 3216;
    float* outF   = (float*)d_out;

    const int M = 128 * 200;  // 25600

    transpose_wasp<<<dim3(2048), dim3(128), 0, stream>>>(W_asp, Wt);
    gather_kernel<<<dim3(128 * 201 + 128 * 200), dim3(128), 0, stream>>>(
        item_emb, log_seqs, pos_seqs, neg_seqs, kvx, negx, validE, validL);
    aspects_kernel<1><<<dim3(3216), dim3(256), 0, stream>>>(
        kvx, Wt, w_weight, validE, G, pInd, pCent, 128 * 201);
    aspects_kernel<0><<<dim3(3200), dim3(256), 0, stream>>>(
        negx, Wt, w_weight, validL, negt, nullptr, nullptr, 128 * 200);
    reduce_kernel<<<dim3(1), dim3(256), 0, stream>>>(
        pInd, pCent, 3216, validE, 128 * 201, outF + 51200);
    seqs_init<<<dim3(12800), dim3(256), 0, stream>>>(G, pos_emb, validL, seqs);

    for (int i = 0; i < 2; ++i) {
        const float* Wq = inW + (size_t)i * 384 * 128;
        const float* Wk = Wq + 128 * 128;
        const float* Wv = Wk + 128 * 128;
        const float* bq = inB + (size_t)i * 384;
        const float* bk = bq + 128;
        const float* bv = bk + 128;
        ln_kernel<<<dim3(6400), dim3(256), 0, stream>>>(seqs, attn_g + i * 128, attn_b + i * 128, Qn, M);
        gemm128_kernel<0, 0, 0><<<dim3(400), dim3(256), 0, stream>>>(Qn,   Wq, bq, nullptr, nullptr, qp, M);
        gemm128_kernel<0, 0, 0><<<dim3(400), dim3(256), 0, stream>>>(seqs, Wk, bk, nullptr, nullptr, kp, M);
        gemm128_kernel<0, 0, 0><<<dim3(400), dim3(256), 0, stream>>>(seqs, Wv, bv, nullptr, nullptr, vp, M);
        attn_kernel<<<dim3(256), dim3(256), 0, stream>>>(qp, kp, vp, attno);
        gemm128_kernel<0, 1, 0><<<dim3(400), dim3(256), 0, stream>>>(
            attno, outW + (size_t)i * 128 * 128, outB + i * 128, Qn, nullptr, seqs, M);
        ln_kernel<<<dim3(6400), dim3(256), 0, stream>>>(seqs, fwd_g + i * 128, fwd_b + i * 128, Qn, M);
        gemm128_kernel<1, 0, 0><<<dim3(400), dim3(256), 0, stream>>>(
            Qn, c1w + (size_t)i * 128 * 128, c1b + i * 128, nullptr, nullptr, qp, M);
        gemm128_kernel<0, 1, 1><<<dim3(400), dim3(256), 0, stream>>>(
            qp, c2w + (size_t)i * 128 * 128, c2b + i * 128, Qn, validL, seqs, M);
    }
    ln_kernel<<<dim3(6400), dim3(256), 0, stream>>>(seqs, last_g, last_b, Qn, M);
    logits_kernel<<<dim3(6400), dim3(256), 0, stream>>>(Qn, G, negt, validL, outF);
}

// Round 3
// 724.259 us; speedup vs baseline: 3.5291x; 2.3315x over previous
//
#include <hip/hip_runtime.h>
#include <cstddef>

// Problem constants: N=128, L=200, LE=201, E=128, A=16 aspects, NB=2, H=2, HD=64, TEMP=0.2
typedef __attribute__((ext_vector_type(8))) short bf16x8;
typedef __attribute__((ext_vector_type(4))) float f32x4;
typedef unsigned short ushort_t;

__device__ __forceinline__ short f2bf(float f) {
    unsigned u = __builtin_bit_cast(unsigned, f);
    u = (u + 0x7FFFu + ((u >> 16) & 1u)) >> 16;
    return (short)u;
}
__device__ __forceinline__ float bf2f(short s) {
    unsigned u = ((unsigned)(unsigned short)s) << 16;
    return __builtin_bit_cast(float, u);
}

// ---------------------------------------------------------------------------
__global__ void cvt_bf16(const float* __restrict__ src, ushort_t* __restrict__ dst, int n) {
    const int i = blockIdx.x * 256 + threadIdx.x;
    if (i < n) dst[i] = (ushort_t)f2bf(src[i]);
}

// ---------------------------------------------------------------------------
// Gather embeddings + valid flags.
__global__ void gather_kernel(const float* __restrict__ item_emb,
                              const int* __restrict__ log_seqs,
                              const int* __restrict__ pos_seqs,
                              const int* __restrict__ neg_seqs,
                              float* __restrict__ kvx, float* __restrict__ negx,
                              float* __restrict__ validE, float* __restrict__ validL) {
    const int r = blockIdx.x;
    const int e = threadIdx.x;     // 128 threads
    const int NKV = 128 * 201;
    if (r < NKV) {
        const int n = r / 201, l = r % 201;
        float vl; int sidx;
        if (l < 200) { sidx = log_seqs[n * 200 + l]; vl = (sidx != 0) ? 1.f : 0.f; }
        else { vl = (log_seqs[n * 200 + 199] != 0) ? 1.f : 0.f; sidx = pos_seqs[n * 200 + 199]; }
        kvx[(size_t)r * 128 + e] = item_emb[(size_t)sidx * 128 + e] * vl;
        if (e == 0) validE[r] = vl;
    } else {
        const int rr = r - NKV;
        const int n = rr / 200, l = rr % 200;
        const float vl = (log_seqs[n * 200 + l] != 0) ? 1.f : 0.f;
        const int sidx = neg_seqs[n * 200 + l];
        negx[(size_t)rr * 128 + e] = item_emb[(size_t)sidx * 128 + e] * vl;
        if (e == 0) validL[rr] = vl;
    }
}

// ---------------------------------------------------------------------------
// Fused MFMA aspects kernel. 16 rows/block, 256 threads = 4 waves.
// Wave w computes aspects 4w..4w+3 over all 16 rows via 16x16x32 bf16 MFMA.
// Norm^2 and gate-logit partials accumulated in-register during the epilogue.
// Gram (ind_loss) = one 16x16x128 MFMA per row where A-frag == B-frag.
template <int LOSSES>
__global__ __launch_bounds__(256, 2) void aspects_kernel(
        const float* __restrict__ X, const ushort_t* __restrict__ Wab,
        const float* __restrict__ w_weight, const float* __restrict__ validf,
        float* __restrict__ Gout, float* __restrict__ pInd, float* __restrict__ pCent) {
    __shared__ short rsb[16 * 2176];       // v=r+x, bf16, [row][a*136 + o]
    __shared__ float xs[16][132];          // x fp32, padded
    __shared__ float s_red[256];           // nrm2 -> sg
    __shared__ float s_lg[256];            // raw logit -> gateW
    __shared__ float s_pos[256];           // pos_s*5
    __shared__ float vld[16];
    __shared__ float centw[16];
    __shared__ float miw[16];

    const int tid = threadIdx.x;
    const int row0 = blockIdx.x * 16;
    const int lane = tid & 63, w = tid >> 6;
    const int q = lane >> 4, nn = lane & 15;
    const float* wa_g = w_weight + 128;

    // stage x (16 rows x 128 fp32)
    for (int t = tid; t < 512; t += 256) {
        const int r = t >> 5, c4 = (t & 31) * 4;
        *(float4*)&xs[r][c4] = *(const float4*)&X[(size_t)(row0 + r) * 128 + c4];
    }
    if (tid < 16) vld[tid] = validf[row0 + tid];
    __syncthreads();

    // A fragments (shared across waves): A[m][k], m=lane&15, k=(lane>>4)*8+f*32+j
    bf16x8 af[4];
#pragma unroll
    for (int f = 0; f < 4; ++f) {
        const float* px = &xs[nn][f * 32 + q * 8];
        bf16x8 v;
#pragma unroll
        for (int j = 0; j < 8; ++j) v[j] = f2bf(px[j]);
        af[f] = v;
    }
    float wav8[8];
#pragma unroll
    for (int t = 0; t < 8; ++t) wav8[t] = wa_g[t * 16 + nn];

    // ---- GEMM phase: 4 aspects per wave, 8 N-tiles each ----
    for (int al = 0; al < 4; ++al) {
        const int a = w * 4 + al;
        float np[4] = {0.f, 0.f, 0.f, 0.f}, lp[4] = {0.f, 0.f, 0.f, 0.f};
#pragma unroll
        for (int t = 0; t < 8; ++t) {
            const int n = a * 128 + t * 16 + nn;
            f32x4 d = {0.f, 0.f, 0.f, 0.f};
#pragma unroll
            for (int f = 0; f < 4; ++f) {
                bf16x8 b = *(const bf16x8*)&Wab[(size_t)n * 128 + f * 32 + q * 8];
                d = __builtin_amdgcn_mfma_f32_16x16x32_bf16(af[f], b, d, 0, 0, 0);
            }
            const int o = t * 16 + nn;
            const float wav = wav8[t];
#pragma unroll
            for (int r = 0; r < 4; ++r) {
                const int row = q * 4 + r;
                const float v = d[r] + xs[row][o];
                np[r] += v * v;
                lp[r] += v * wav;
                rsb[row * 2176 + a * 136 + o] = f2bf(v);
            }
        }
#pragma unroll
        for (int m = 1; m < 16; m <<= 1) {
#pragma unroll
            for (int r = 0; r < 4; ++r) {
                np[r] += __shfl_xor(np[r], m, 16);
                lp[r] += __shfl_xor(lp[r], m, 16);
            }
        }
        if (nn == 0) {
#pragma unroll
            for (int r = 0; r < 4; ++r) {
                s_red[(q * 4 + r) * 16 + a] = np[r];
                s_lg[(q * 4 + r) * 16 + a] = lp[r];
            }
        }
    }
    __syncthreads();

    // ---- per-(row,aspect) scalars + gate softmax (tid = row*16 + a) ----
    {
        const float nrm = sqrtf(s_red[tid]);
        const float inv1 = 1.f / (nrm + 1e-8f);
        const float n2 = nrm * inv1;
        const float sg = inv1 / (n2 + 1e-8f);
        const float ts = n2 / (n2 + 1e-8f);
        const float logit = s_lg[tid] * inv1;
        float mx = logit;
#pragma unroll
        for (int m = 1; m < 16; m <<= 1) mx = fmaxf(mx, __shfl_xor(mx, m, 16));
        const float e = __expf(logit - mx);
        float ssum = e;
#pragma unroll
        for (int m = 1; m < 16; m <<= 1) ssum += __shfl_xor(ssum, m, 16);
        s_red[tid] = sg;
        s_pos[tid] = ts * ts * 5.f;
        s_lg[tid] = (e / ssum + 0.0625f) * inv1;
    }
    __syncthreads();

    // ---- per-row outputs: G (+cent, +gram/mi) ----
    for (int rl = 0; rl < 4; ++rl) {
        const int row = w * 4 + rl;
        const int o2 = lane * 2;
        float g0 = 0.f, g1 = 0.f, sr0 = 0.f, sr1 = 0.f;
#pragma unroll
        for (int a = 0; a < 16; ++a) {
            const unsigned pk = *(const unsigned*)&rsb[row * 2176 + a * 136 + o2];
            const float v0 = bf2f((short)(pk & 0xFFFF));
            const float v1 = bf2f((short)(pk >> 16));
            const float gw = s_lg[row * 16 + a];
            g0 += v0 * gw; g1 += v1 * gw;
            if (LOSSES) { sr0 += v0; sr1 += v1; }
        }
        *(float2*)&Gout[(size_t)(row0 + row) * 128 + o2] = make_float2(g0, g1);
        if constexpr (LOSSES) {
            float d0 = 2.f * xs[row][o2]     - sr0 * 0.0625f;
            float d1 = 2.f * xs[row][o2 + 1] - sr1 * 0.0625f;
            float c = d0 * d0 + d1 * d1;
#pragma unroll
            for (int m = 1; m < 64; m <<= 1) c += __shfl_xor(c, m, 64);
            if (lane == 0) centw[row] = sqrtf(c) * vld[row];
            // gram via MFMA: frag = v[aspect=nn][k], A-frag == B-frag
            f32x4 dd = {0.f, 0.f, 0.f, 0.f};
#pragma unroll
            for (int f = 0; f < 4; ++f) {
                bf16x8 fr = *(const bf16x8*)&rsb[row * 2176 + nn * 136 + f * 32 + q * 8];
                dd = __builtin_amdgcn_mfma_f32_16x16x32_bf16(fr, fr, dd, 0, 0, 0);
            }
            const float sgb = s_red[row * 16 + nn];
            float mis = 0.f;
#pragma unroll
            for (int r = 0; r < 4; ++r) {
                const int a = q * 4 + r;
                const float sga = s_red[row * 16 + a];
                float eb = __expf(5.f * dd[r] * sga * sgb);
#pragma unroll
                for (int m = 1; m < 16; m <<= 1) eb += __shfl_xor(eb, m, 16);
                mis += -(s_pos[row * 16 + a] - logf(eb));
            }
            mis += __shfl_xor(mis, 16, 64);
            mis += __shfl_xor(mis, 32, 64);
            if (lane == 0) miw[row] = mis * vld[row];
        }
    }
    if constexpr (LOSSES) {
        __syncthreads();
        if (tid == 0) {
            float si = 0.f, sc = 0.f;
#pragma unroll
            for (int r = 0; r < 16; ++r) { si += miw[r]; sc += centw[r]; }
            pInd[blockIdx.x] = si;
            pCent[blockIdx.x] = sc;
        }
    }
}

// ---------------------------------------------------------------------------
// MFMA GEMM: C[M x 128] = X[M x 128] @ Wb^T (+bias)(+res)(relu)(*mask)
// EPI: 0 = bias; 1 = bias+relu; 2 = bias+res; 3 = bias+res+mask
template <int EPI>
__global__ __launch_bounds__(256) void mgemm(const float* __restrict__ X,
                                             const ushort_t* __restrict__ Wb,
                                             const float* __restrict__ bias,
                                             const float* __restrict__ res,
                                             const float* __restrict__ mask,
                                             float* __restrict__ C) {
    const int tid = threadIdx.x, lane = tid & 63, w = tid >> 6;
    const int q = lane >> 4, nn = lane & 15;
    const int m0 = blockIdx.x * 64 + w * 16;
    bf16x8 af[4];
    const float* xr = &X[(size_t)(m0 + nn) * 128];
#pragma unroll
    for (int f = 0; f < 4; ++f) {
        const float* px = &xr[f * 32 + q * 8];
        bf16x8 v;
#pragma unroll
        for (int j = 0; j < 8; ++j) v[j] = f2bf(px[j]);
        af[f] = v;
    }
    f32x4 acc[8];
#pragma unroll
    for (int t = 0; t < 8; ++t) acc[t] = (f32x4){0.f, 0.f, 0.f, 0.f};
#pragma unroll
    for (int t = 0; t < 8; ++t) {
#pragma unroll
        for (int f = 0; f < 4; ++f) {
            bf16x8 b = *(const bf16x8*)&Wb[(size_t)(t * 16 + nn) * 128 + f * 32 + q * 8];
            acc[t] = __builtin_amdgcn_mfma_f32_16x16x32_bf16(af[f], b, acc[t], 0, 0, 0);
        }
    }
    float mk[4];
    if (EPI == 3) {
#pragma unroll
        for (int r = 0; r < 4; ++r) mk[r] = mask[m0 + q * 4 + r];
    }
#pragma unroll
    for (int t = 0; t < 8; ++t) {
        const int n = t * 16 + nn;
        const float bi = bias[n];
#pragma unroll
        for (int r = 0; r < 4; ++r) {
            const int row = m0 + q * 4 + r;
            float v = acc[t][r] + bi;
            if (EPI >= 2) v += res[(size_t)row * 128 + n];
            if (EPI == 1) v = fmaxf(v, 0.f);
            if (EPI == 3) v *= mk[r];
            C[(size_t)row * 128 + n] = v;
        }
    }
}

// ---------------------------------------------------------------------------
__global__ void reduce_kernel(const float* __restrict__ pInd, const float* __restrict__ pCent,
                              int nblk, const float* __restrict__ validE, int nve,
                              float* __restrict__ outp) {
    __shared__ float a1[256], a2[256], a3[256];
    const int tid = threadIdx.x;
    float si = 0.f, sc = 0.f, nv = 0.f;
    for (int t = tid; t < nblk; t += 256) { si += pInd[t]; sc += pCent[t]; }
    for (int t = tid; t < nve; t += 256) nv += validE[t];
    a1[tid] = si; a2[tid] = sc; a3[tid] = nv;
    __syncthreads();
    for (int s = 128; s > 0; s >>= 1) {
        if (tid < s) { a1[tid] += a1[tid + s]; a2[tid] += a2[tid + s]; a3[tid] += a3[tid + s]; }
        __syncthreads();
    }
    if (tid == 0) { outp[0] = a1[0] / a3[0]; outp[1] = a2[0] / a3[0]; }
}

// ---------------------------------------------------------------------------
__global__ void seqs_init(const float* __restrict__ G, const float* __restrict__ pos_emb,
                          const float* __restrict__ validL, float* __restrict__ seqs) {
    const int idx = blockIdx.x * 256 + threadIdx.x;
    const int e = idx & 127;
    const int nl = idx >> 7;
    const int l = nl % 200, n = nl / 200;
    const float v = G[((size_t)n * 201 + l) * 128 + e] * 11.313708498984761f + pos_emb[l * 128 + e];
    seqs[idx] = v * validL[nl];
}

// ---------------------------------------------------------------------------
__global__ __launch_bounds__(256) void ln_kernel(const float* __restrict__ X,
                                                 const float* __restrict__ g,
                                                 const float* __restrict__ b,
                                                 float* __restrict__ Y, int M) {
    const int row = blockIdx.x * 4 + (threadIdx.x >> 6);
    const int lane = threadIdx.x & 63;
    if (row >= M) return;
    const float2 x = *(const float2*)&X[(size_t)row * 128 + lane * 2];
    float s = x.x + x.y, sq = x.x * x.x + x.y * x.y;
#pragma unroll
    for (int m = 1; m < 64; m <<= 1) { s += __shfl_xor(s, m, 64); sq += __shfl_xor(sq, m, 64); }
    const float mean = s * 0.0078125f;
    const float var = fmaxf(sq * 0.0078125f - mean * mean, 0.f);
    const float inv = rsqrtf(var + 1e-8f);
    const float2 gg = *(const float2*)&g[lane * 2];
    const float2 bb = *(const float2*)&b[lane * 2];
    float2 y;
    y.x = (x.x - mean) * inv * gg.x + bb.x;
    y.y = (x.y - mean) * inv * gg.y + bb.y;
    *(float2*)&Y[(size_t)row * 128 + lane * 2] = y;
}

// ---------------------------------------------------------------------------
// Flash-style causal attention: one block per (n,h), one query per thread.
__global__ __launch_bounds__(256) void attn_kernel(const float* __restrict__ qp,
                                                   const float* __restrict__ kp,
                                                   const float* __restrict__ vp,
                                                   float* __restrict__ outp) {
    constexpr int TJ = 32;
    __shared__ float Ks[TJ][64];
    __shared__ float Vs[TJ][64];
    const int tid = threadIdx.x;
    const int n = blockIdx.x >> 1, h = blockIdx.x & 1;
    const size_t base = ((size_t)n * 200) * 128 + (size_t)h * 64;
    const int qrow = tid;
    float qv[64], ov[64];
    float mrun = -3.0e38f, lrun = 0.f;
    if (qrow < 200) {
#pragma unroll
        for (int e = 0; e < 64; e += 4)
            *(float4*)&qv[e] = *(const float4*)&qp[base + (size_t)qrow * 128 + e];
    }
#pragma unroll
    for (int e = 0; e < 64; ++e) ov[e] = 0.f;

    for (int jt = 0; jt < 200; jt += TJ) {
        const int nj = min(TJ, 200 - jt);
        for (int t = tid; t < TJ * 16; t += 256) {
            const int j = t >> 4, c4 = (t & 15) << 2;
            float4 kvt = make_float4(0.f, 0.f, 0.f, 0.f), vvt = kvt;
            if (j < nj) {
                kvt = *(const float4*)&kp[base + (size_t)(jt + j) * 128 + c4];
                vvt = *(const float4*)&vp[base + (size_t)(jt + j) * 128 + c4];
            }
            *(float4*)&Ks[j][c4] = kvt;
            *(float4*)&Vs[j][c4] = vvt;
        }
        __syncthreads();
        if (qrow < 200 && jt <= qrow) {
            const int jmax = min(nj, qrow - jt + 1);
            for (int j0 = 0; j0 < jmax; j0 += 8) {
                const int jn = jmax - j0;
                float s[8];
                float cmax = mrun;
#pragma unroll
                for (int j = 0; j < 8; ++j) {
                    float a0 = 0.f, a1 = 0.f, a2 = 0.f, a3 = 0.f;
#pragma unroll
                    for (int e = 0; e < 64; e += 4) {
                        const float4 k4 = *(const float4*)&Ks[j0 + j][e];
                        a0 += qv[e]     * k4.x;
                        a1 += qv[e + 1] * k4.y;
                        a2 += qv[e + 2] * k4.z;
                        a3 += qv[e + 3] * k4.w;
                    }
                    s[j] = (j < jn) ? ((a0 + a1) + (a2 + a3)) * 0.125f : -3.0e38f;
                    cmax = fmaxf(cmax, s[j]);
                }
                if (cmax > mrun) {
                    const float c = __expf(mrun - cmax);
                    lrun *= c;
#pragma unroll
                    for (int e = 0; e < 64; ++e) ov[e] *= c;
                    mrun = cmax;
                }
#pragma unroll
                for (int j = 0; j < 8; ++j) {
                    const float p = __expf(s[j] - mrun);
                    lrun += p;
#pragma unroll
                    for (int e = 0; e < 64; e += 4) {
                        const float4 v4 = *(const float4*)&Vs[j0 + j][e];
                        ov[e]     += p * v4.x;
                        ov[e + 1] += p * v4.y;
                        ov[e + 2] += p * v4.z;
                        ov[e + 3] += p * v4.w;
                    }
                }
            }
        }
        __syncthreads();
    }
    if (qrow < 200) {
        const float inv = 1.f / lrun;
#pragma unroll
        for (int e = 0; e < 64; e += 4) {
            const float4 o4 = make_float4(ov[e] * inv, ov[e + 1] * inv,
                                          ov[e + 2] * inv, ov[e + 3] * inv);
            *(float4*)&outp[base + (size_t)qrow * 128 + e] = o4;
        }
    }
}

// ---------------------------------------------------------------------------
__global__ __launch_bounds__(256) void logits_kernel(const float* __restrict__ lf,
                                                     const float* __restrict__ G,
                                                     const float* __restrict__ negt,
                                                     const float* __restrict__ validL,
                                                     float* __restrict__ outp) {
    const int row = blockIdx.x * 4 + (threadIdx.x >> 6);
    const int lane = threadIdx.x & 63;
    if (row >= 25600) return;
    const int n = row / 200, j = row % 200;
    const float2 x  = *(const float2*)&lf[(size_t)row * 128 + lane * 2];
    const float2 g2 = *(const float2*)&G[((size_t)n * 201 + j + 1) * 128 + lane * 2];
    const float2 t2 = *(const float2*)&negt[(size_t)row * 128 + lane * 2];
    float sp = x.x * g2.x + x.y * g2.y;
    float sn = x.x * t2.x + x.y * t2.y;
#pragma unroll
    for (int m = 1; m < 64; m <<= 1) { sp += __shfl_xor(sp, m, 64); sn += __shfl_xor(sn, m, 64); }
    if (lane == 0) { outp[row] = sp * validL[row]; outp[25600 + row] = sn; }
}

// ---------------------------------------------------------------------------
extern "C" void kernel_launch(void* const* d_in, const int* in_sizes, int n_in,
                              void* d_out, int out_size, void* d_ws, size_t ws_size,
                              hipStream_t stream) {
    (void)in_sizes; (void)n_in; (void)out_size; (void)ws_size;
    const float* item_emb = (const float*)d_in[0];
    const float* pos_emb  = (const float*)d_in[1];
    const float* W_asp    = (const float*)d_in[2];
    const float* w_weight = (const float*)d_in[3];
    // d_in[4] w_bias: cancels in aspect softmax (shift invariance)
    const float* attn_g = (const float*)d_in[5];
    const float* attn_b = (const float*)d_in[6];
    const float* inW    = (const float*)d_in[7];
    const float* inB    = (const float*)d_in[8];
    const float* outW   = (const float*)d_in[9];
    const float* outB   = (const float*)d_in[10];
    const float* fwd_g  = (const float*)d_in[11];
    const float* fwd_b  = (const float*)d_in[12];
    const float* c1w    = (const float*)d_in[13];
    const float* c1b    = (const float*)d_in[14];
    const float* c2w    = (const float*)d_in[15];
    const float* c2b    = (const float*)d_in[16];
    const float* last_g = (const float*)d_in[17];
    const float* last_b = (const float*)d_in[18];
    const int* log_seqs = (const int*)d_in[20];
    const int* pos_seqs = (const int*)d_in[21];
    const int* neg_seqs = (const int*)d_in[22];

    float* ws = (float*)d_ws;
    const size_t S = (size_t)128 * 201 * 128;  // one (N, 201, 128) slot
    float* kvx   = ws;           float* qp = kvx;   // reuse after aspects<1>
    float* negx  = ws + S;       float* kp = negx;  // reuse after aspects<0>
    float* G     = ws + 2 * S;
    float* negt  = ws + 3 * S;
    float* seqs  = ws + 4 * S;
    float* Qn    = ws + 5 * S;
    float* vp    = ws + 6 * S;
    float* attno = ws + 7 * S;
    ushort_t* wb  = (ushort_t*)(ws + 8 * S);
    ushort_t* Wab  = wb;                    // 262144
    ushort_t* inWb = Wab + 262144;          // 98304
    ushort_t* outWb = inWb + 98304;         // 32768
    ushort_t* c1b_w = outWb + 32768;        // 32768
    ushort_t* c2b_w = c1b_w + 32768;        // 32768
    float* validE = ws + 8 * S + 229376;
    float* validL = validE + 128 * 201;
    float* pInd   = validL + 128 * 200;
    float* pCent  = pInd + 1608;
    float* outF   = (float*)d_out;

    const int M = 128 * 200;  // 25600

    cvt_bf16<<<dim3(1024), dim3(256), 0, stream>>>(W_asp, Wab, 262144);
    cvt_bf16<<<dim3(384),  dim3(256), 0, stream>>>(inW,  inWb, 98304);
    cvt_bf16<<<dim3(128),  dim3(256), 0, stream>>>(outW, outWb, 32768);
    cvt_bf16<<<dim3(128),  dim3(256), 0, stream>>>(c1w,  c1b_w, 32768);
    cvt_bf16<<<dim3(128),  dim3(256), 0, stream>>>(c2w,  c2b_w, 32768);
    gather_kernel<<<dim3(128 * 201 + 128 * 200), dim3(128), 0, stream>>>(
        item_emb, log_seqs, pos_seqs, neg_seqs, kvx, negx, validE, validL);
    aspects_kernel<1><<<dim3(1608), dim3(256), 0, stream>>>(
        kvx, Wab, w_weight, validE, G, pInd, pCent);
    aspects_kernel<0><<<dim3(1600), dim3(256), 0, stream>>>(
        negx, Wab, w_weight, validL, negt, nullptr, nullptr);
    reduce_kernel<<<dim3(1), dim3(256), 0, stream>>>(
        pInd, pCent, 1608, validE, 128 * 201, outF + 51200);
    seqs_init<<<dim3(12800), dim3(256), 0, stream>>>(G, pos_emb, validL, seqs);

    for (int i = 0; i < 2; ++i) {
        const ushort_t* Wq = inWb + (size_t)i * 384 * 128;
        const ushort_t* Wk = Wq + 128 * 128;
        const ushort_t* Wv = Wk + 128 * 128;
        const float* bq = inB + (size_t)i * 384;
        const float* bk = bq + 128;
        const float* bv = bk + 128;
        ln_kernel<<<dim3(6400), dim3(256), 0, stream>>>(seqs, attn_g + i * 128, attn_b + i * 128, Qn, M);
        mgemm<0><<<dim3(400), dim3(256), 0, stream>>>(Qn,   Wq, bq, nullptr, nullptr, qp);
        mgemm<0><<<dim3(400), dim3(256), 0, stream>>>(seqs, Wk, bk, nullptr, nullptr, kp);
        mgemm<0><<<dim3(400), dim3(256), 0, stream>>>(seqs, Wv, bv, nullptr, nullptr, vp);
        attn_kernel<<<dim3(256), dim3(256), 0, stream>>>(qp, kp, vp, attno);
        mgemm<2><<<dim3(400), dim3(256), 0, stream>>>(
            attno, outWb + (size_t)i * 128 * 128, outB + i * 128, Qn, nullptr, seqs);
        ln_kernel<<<dim3(6400), dim3(256), 0, stream>>>(seqs, fwd_g + i * 128, fwd_b + i * 128, Qn, M);
        mgemm<1><<<dim3(400), dim3(256), 0, stream>>>(
            Qn, c1b_w + (size_t)i * 128 * 128, c1b + i * 128, nullptr, nullptr, qp);
        mgemm<3><<<dim3(400), dim3(256), 0, stream>>>(
            qp, c2b_w + (size_t)i * 128 * 128, c2b + i * 128, Qn, validL, seqs);
    }
    ln_kernel<<<dim3(6400), dim3(256), 0, stream>>>(seqs, last_g, last_b, Qn, M);
    logits_kernel<<<dim3(6400), dim3(256), 0, stream>>>(Qn, G, negt, validL, outF);
}

// Round 5
// 534.770 us; speedup vs baseline: 4.7795x; 1.3543x over previous
//
#include <hip/hip_runtime.h>
#include <cstddef>

// Problem constants: N=128, L=200, LE=201, E=128, A=16 aspects, NB=2, H=2, HD=64, TEMP=0.2
typedef __attribute__((ext_vector_type(8))) short bf16x8;
typedef __attribute__((ext_vector_type(4))) float f32x4;
typedef unsigned short ushort_t;

__device__ __forceinline__ short f2bf(float f) {
    unsigned u = __builtin_bit_cast(unsigned, f);
    u = (u + 0x7FFFu + ((u >> 16) & 1u)) >> 16;
    return (short)u;
}
__device__ __forceinline__ float bf2f(short s) {
    unsigned u = ((unsigned)(unsigned short)s) << 16;
    return __builtin_bit_cast(float, u);
}
__device__ __forceinline__ unsigned pk2(float a, float b) {
    return (unsigned)(unsigned short)f2bf(a) | ((unsigned)(unsigned short)f2bf(b) << 16);
}

// ---------------------------------------------------------------------------
__global__ void cvt_bf16(const float* __restrict__ src, ushort_t* __restrict__ dst, int n) {
    const int i = blockIdx.x * 256 + threadIdx.x;
    if (i < n) dst[i] = (ushort_t)f2bf(src[i]);
}

// ---------------------------------------------------------------------------
__global__ void gather_kernel(const float* __restrict__ item_emb,
                              const int* __restrict__ log_seqs,
                              const int* __restrict__ pos_seqs,
                              const int* __restrict__ neg_seqs,
                              float* __restrict__ kvx, float* __restrict__ negx,
                              float* __restrict__ validE, float* __restrict__ validL) {
    const int r = blockIdx.x;
    const int e = threadIdx.x;     // 128 threads
    const int NKV = 128 * 201;
    if (r < NKV) {
        const int n = r / 201, l = r % 201;
        float vl; int sidx;
        if (l < 200) { sidx = log_seqs[n * 200 + l]; vl = (sidx != 0) ? 1.f : 0.f; }
        else { vl = (log_seqs[n * 200 + 199] != 0) ? 1.f : 0.f; sidx = pos_seqs[n * 200 + 199]; }
        kvx[(size_t)r * 128 + e] = item_emb[(size_t)sidx * 128 + e] * vl;
        if (e == 0) validE[r] = vl;
    } else {
        const int rr = r - NKV;
        const int n = rr / 200, l = rr % 200;
        const float vl = (log_seqs[n * 200 + l] != 0) ? 1.f : 0.f;
        const int sidx = neg_seqs[n * 200 + l];
        negx[(size_t)rr * 128 + e] = item_emb[(size_t)sidx * 128 + e] * vl;
        if (e == 0) validL[rr] = vl;
    }
}

// ---------------------------------------------------------------------------
// Fused MFMA aspects kernel. 16 rows/block, 256 threads = 4 waves.
template <int LOSSES>
__global__ __launch_bounds__(256, 2) void aspects_kernel(
        const float* __restrict__ X, const ushort_t* __restrict__ Wab,
        const float* __restrict__ w_weight, const float* __restrict__ validf,
        float* __restrict__ Gout, float* __restrict__ pInd, float* __restrict__ pCent) {
    __shared__ short rsb[16 * 2176];       // v=r+x, bf16, [row][a*136 + o]
    __shared__ float xs[16][132];          // x fp32, padded
    __shared__ float s_red[256];           // nrm2 -> sg
    __shared__ float s_lg[256];            // raw logit -> gateW
    __shared__ float s_pos[256];           // pos_s*5
    __shared__ float vld[16];
    __shared__ float centw[16];
    __shared__ float miw[16];

    const int tid = threadIdx.x;
    const int row0 = blockIdx.x * 16;
    const int lane = tid & 63, w = tid >> 6;
    const int q = lane >> 4, nn = lane & 15;
    const float* wa_g = w_weight + 128;

    for (int t = tid; t < 512; t += 256) {
        const int r = t >> 5, c4 = (t & 31) * 4;
        *(float4*)&xs[r][c4] = *(const float4*)&X[(size_t)(row0 + r) * 128 + c4];
    }
    if (tid < 16) vld[tid] = validf[row0 + tid];
    __syncthreads();

    bf16x8 af[4];
#pragma unroll
    for (int f = 0; f < 4; ++f) {
        const float* px = &xs[nn][f * 32 + q * 8];
        bf16x8 v;
#pragma unroll
        for (int j = 0; j < 8; ++j) v[j] = f2bf(px[j]);
        af[f] = v;
    }
    float wav8[8];
#pragma unroll
    for (int t = 0; t < 8; ++t) wav8[t] = wa_g[t * 16 + nn];

    for (int al = 0; al < 4; ++al) {
        const int a = w * 4 + al;
        float np[4] = {0.f, 0.f, 0.f, 0.f}, lp[4] = {0.f, 0.f, 0.f, 0.f};
#pragma unroll
        for (int t = 0; t < 8; ++t) {
            const int n = a * 128 + t * 16 + nn;
            f32x4 d = {0.f, 0.f, 0.f, 0.f};
#pragma unroll
            for (int f = 0; f < 4; ++f) {
                bf16x8 b = *(const bf16x8*)&Wab[(size_t)n * 128 + f * 32 + q * 8];
                d = __builtin_amdgcn_mfma_f32_16x16x32_bf16(af[f], b, d, 0, 0, 0);
            }
            const int o = t * 16 + nn;
            const float wav = wav8[t];
#pragma unroll
            for (int r = 0; r < 4; ++r) {
                const int row = q * 4 + r;
                const float v = d[r] + xs[row][o];
                np[r] += v * v;
                lp[r] += v * wav;
                rsb[row * 2176 + a * 136 + o] = f2bf(v);
            }
        }
#pragma unroll
        for (int m = 1; m < 16; m <<= 1) {
#pragma unroll
            for (int r = 0; r < 4; ++r) {
                np[r] += __shfl_xor(np[r], m, 16);
                lp[r] += __shfl_xor(lp[r], m, 16);
            }
        }
        if (nn == 0) {
#pragma unroll
            for (int r = 0; r < 4; ++r) {
                s_red[(q * 4 + r) * 16 + a] = np[r];
                s_lg[(q * 4 + r) * 16 + a] = lp[r];
            }
        }
    }
    __syncthreads();

    {
        const float nrm = sqrtf(s_red[tid]);
        const float inv1 = 1.f / (nrm + 1e-8f);
        const float n2 = nrm * inv1;
        const float sg = inv1 / (n2 + 1e-8f);
        const float ts = n2 / (n2 + 1e-8f);
        const float logit = s_lg[tid] * inv1;
        float mx = logit;
#pragma unroll
        for (int m = 1; m < 16; m <<= 1) mx = fmaxf(mx, __shfl_xor(mx, m, 16));
        const float e = __expf(logit - mx);
        float ssum = e;
#pragma unroll
        for (int m = 1; m < 16; m <<= 1) ssum += __shfl_xor(ssum, m, 16);
        s_red[tid] = sg;
        s_pos[tid] = ts * ts * 5.f;
        s_lg[tid] = (e / ssum + 0.0625f) * inv1;
    }
    __syncthreads();

    for (int rl = 0; rl < 4; ++rl) {
        const int row = w * 4 + rl;
        const int o2 = lane * 2;
        float g0 = 0.f, g1 = 0.f, sr0 = 0.f, sr1 = 0.f;
#pragma unroll
        for (int a = 0; a < 16; ++a) {
            const unsigned pk = *(const unsigned*)&rsb[row * 2176 + a * 136 + o2];
            const float v0 = bf2f((short)(pk & 0xFFFF));
            const float v1 = bf2f((short)(pk >> 16));
            const float gw = s_lg[row * 16 + a];
            g0 += v0 * gw; g1 += v1 * gw;
            if (LOSSES) { sr0 += v0; sr1 += v1; }
        }
        *(float2*)&Gout[(size_t)(row0 + row) * 128 + o2] = make_float2(g0, g1);
        if constexpr (LOSSES) {
            float d0 = 2.f * xs[row][o2]     - sr0 * 0.0625f;
            float d1 = 2.f * xs[row][o2 + 1] - sr1 * 0.0625f;
            float c = d0 * d0 + d1 * d1;
#pragma unroll
            for (int m = 1; m < 64; m <<= 1) c += __shfl_xor(c, m, 64);
            if (lane == 0) centw[row] = sqrtf(c) * vld[row];
            f32x4 dd = {0.f, 0.f, 0.f, 0.f};
#pragma unroll
            for (int f = 0; f < 4; ++f) {
                bf16x8 fr = *(const bf16x8*)&rsb[row * 2176 + nn * 136 + f * 32 + q * 8];
                dd = __builtin_amdgcn_mfma_f32_16x16x32_bf16(fr, fr, dd, 0, 0, 0);
            }
            const float sgb = s_red[row * 16 + nn];
            float mis = 0.f;
#pragma unroll
            for (int r = 0; r < 4; ++r) {
                const int a = q * 4 + r;
                const float sga = s_red[row * 16 + a];
                float eb = __expf(5.f * dd[r] * sga * sgb);
#pragma unroll
                for (int m = 1; m < 16; m <<= 1) eb += __shfl_xor(eb, m, 16);
                mis += -(s_pos[row * 16 + a] - logf(eb));
            }
            mis += __shfl_xor(mis, 16, 64);
            mis += __shfl_xor(mis, 32, 64);
            if (lane == 0) miw[row] = mis * vld[row];
        }
    }
    if constexpr (LOSSES) {
        __syncthreads();
        if (tid == 0) {
            float si = 0.f, sc = 0.f;
#pragma unroll
            for (int r = 0; r < 16; ++r) { si += miw[r]; sc += centw[r]; }
            pInd[blockIdx.x] = si;
            pCent[blockIdx.x] = sc;
        }
    }
}

// ---------------------------------------------------------------------------
// MFMA GEMM: C[M x 128] = X[M x 128] @ Wb^T (+bias)(+res)(relu)(*mask)
template <int EPI>
__global__ __launch_bounds__(256) void mgemm(const float* __restrict__ X,
                                             const ushort_t* __restrict__ Wb,
                                             const float* __restrict__ bias,
                                             const float* __restrict__ res,
                                             const float* __restrict__ mask,
                                             float* __restrict__ C) {
    const int tid = threadIdx.x, lane = tid & 63, w = tid >> 6;
    const int q = lane >> 4, nn = lane & 15;
    const int m0 = blockIdx.x * 64 + w * 16;
    bf16x8 af[4];
    const float* xr = &X[(size_t)(m0 + nn) * 128];
#pragma unroll
    for (int f = 0; f < 4; ++f) {
        const float* px = &xr[f * 32 + q * 8];
        bf16x8 v;
#pragma unroll
        for (int j = 0; j < 8; ++j) v[j] = f2bf(px[j]);
        af[f] = v;
    }
    f32x4 acc[8];
#pragma unroll
    for (int t = 0; t < 8; ++t) acc[t] = (f32x4){0.f, 0.f, 0.f, 0.f};
#pragma unroll
    for (int t = 0; t < 8; ++t) {
#pragma unroll
        for (int f = 0; f < 4; ++f) {
            bf16x8 b = *(const bf16x8*)&Wb[(size_t)(t * 16 + nn) * 128 + f * 32 + q * 8];
            acc[t] = __builtin_amdgcn_mfma_f32_16x16x32_bf16(af[f], b, acc[t], 0, 0, 0);
        }
    }
    float mk[4];
    if (EPI == 3) {
#pragma unroll
        for (int r = 0; r < 4; ++r) mk[r] = mask[m0 + q * 4 + r];
    }
#pragma unroll
    for (int t = 0; t < 8; ++t) {
        const int n = t * 16 + nn;
        const float bi = bias[n];
#pragma unroll
        for (int r = 0; r < 4; ++r) {
            const int row = m0 + q * 4 + r;
            float v = acc[t][r] + bi;
            if (EPI >= 2) v += res[(size_t)row * 128 + n];
            if (EPI == 1) v = fmaxf(v, 0.f);
            if (EPI == 3) v *= mk[r];
            C[(size_t)row * 128 + n] = v;
        }
    }
}

// ---------------------------------------------------------------------------
__global__ void reduce_kernel(const float* __restrict__ pInd, const float* __restrict__ pCent,
                              int nblk, const float* __restrict__ validE, int nve,
                              float* __restrict__ outp) {
    __shared__ float a1[256], a2[256], a3[256];
    const int tid = threadIdx.x;
    float si = 0.f, sc = 0.f, nv = 0.f;
    for (int t = tid; t < nblk; t += 256) { si += pInd[t]; sc += pCent[t]; }
    for (int t = tid; t < nve; t += 256) nv += validE[t];
    a1[tid] = si; a2[tid] = sc; a3[tid] = nv;
    __syncthreads();
    for (int s = 128; s > 0; s >>= 1) {
        if (tid < s) { a1[tid] += a1[tid + s]; a2[tid] += a2[tid + s]; a3[tid] += a3[tid + s]; }
        __syncthreads();
    }
    if (tid == 0) { outp[0] = a1[0] / a3[0]; outp[1] = a2[0] / a3[0]; }
}

// ---------------------------------------------------------------------------
__global__ void seqs_init(const float* __restrict__ G, const float* __restrict__ pos_emb,
                          const float* __restrict__ validL, float* __restrict__ seqs) {
    const int idx = blockIdx.x * 256 + threadIdx.x;
    const int e = idx & 127;
    const int nl = idx >> 7;
    const int l = nl % 200, n = nl / 200;
    const float v = G[((size_t)n * 201 + l) * 128 + e] * 11.313708498984761f + pos_emb[l * 128 + e];
    seqs[idx] = v * validL[nl];
}

// ---------------------------------------------------------------------------
__global__ __launch_bounds__(256) void ln_kernel(const float* __restrict__ X,
                                                 const float* __restrict__ g,
                                                 const float* __restrict__ b,
                                                 float* __restrict__ Y, int M) {
    const int row = blockIdx.x * 4 + (threadIdx.x >> 6);
    const int lane = threadIdx.x & 63;
    if (row >= M) return;
    const float2 x = *(const float2*)&X[(size_t)row * 128 + lane * 2];
    float s = x.x + x.y, sq = x.x * x.x + x.y * x.y;
#pragma unroll
    for (int m = 1; m < 64; m <<= 1) { s += __shfl_xor(s, m, 64); sq += __shfl_xor(sq, m, 64); }
    const float mean = s * 0.0078125f;
    const float var = fmaxf(sq * 0.0078125f - mean * mean, 0.f);
    const float inv = rsqrtf(var + 1e-8f);
    const float2 gg = *(const float2*)&g[lane * 2];
    const float2 bb = *(const float2*)&b[lane * 2];
    float2 y;
    y.x = (x.x - mean) * inv * gg.x + bb.x;
    y.y = (x.y - mean) * inv * gg.y + bb.y;
    *(float2*)&Y[(size_t)row * 128 + lane * 2] = y;
}

// ---------------------------------------------------------------------------
// MFMA flash attention. Grid = 256 (n,h) x 4 query-tiles of 64. 4 waves x 16 q.
// S^T = mfma(K, Q): lane&15 = q; softmax stats via shfl_xor(16,32);
// P -> wave-private LDS [q=16][k=32] with row stride 40 ush (2-way banks max);
// O = mfma(P, Vt) in [q][e].
__global__ __launch_bounds__(256) void attn_kernel(const float* __restrict__ qp,
                                                   const float* __restrict__ kp,
                                                   const float* __restrict__ vp,
                                                   float* __restrict__ outp) {
    __shared__ ushort_t KsU[2048];          // K tile 32x64 bf16, XOR-swizzled rows of 128B
    __shared__ ushort_t VtU[2560];          // V^T tile [e=64][k], row stride 40 ush
    __shared__ ushort_t Pb[2560];           // per-wave P [q=16][k=32], row stride 40 ush

    const int tid = threadIdx.x, lane = tid & 63, w = tid >> 6;
    const int b = blockIdx.x;
    const int nh = b >> 2, qt = b & 3;
    const int n = nh >> 1, h = nh & 1;
    const size_t base = (size_t)n * 200 * 128 + (size_t)h * 64;
    const int qw = qt * 64 + w * 16;        // wave's first query
    const bool wactive = qw < 200;
    const int q15 = lane & 15, g4 = lane >> 4;
    const int qglob = qw + q15;             // query this lane scores (S^T layout)

    // Q fragments (B-operand), rows clamped
    bf16x8 qf[2];
    {
        const int qr = (qglob < 200) ? qglob : 199;
        const float* px = &qp[base + (size_t)qr * 128 + g4 * 8];
#pragma unroll
        for (int f = 0; f < 2; ++f) {
            bf16x8 v;
#pragma unroll
            for (int j = 0; j < 8; ++j) v[j] = f2bf(px[f * 32 + j]);
            qf[f] = v;
        }
    }
    f32x4 Oacc[4];
#pragma unroll
    for (int nt = 0; nt < 4; ++nt) Oacc[nt] = (f32x4){0.f, 0.f, 0.f, 0.f};
    float mrun = -1e30f, lrun = 0.f;

    const int kmax = min(200, qt * 64 + 64);
    ushort_t* PbW = Pb + w * 640;

    for (int jt = 0; jt < kmax; jt += 32) {
        __syncthreads();
        // ---- stage K (swizzled) ----
        {
            const int k = tid >> 3, e0 = (tid & 7) * 8;
            const int krow = jt + k;
            float4 a = make_float4(0.f, 0.f, 0.f, 0.f), c = a;
            if (krow < 200) {
                a = *(const float4*)&kp[base + (size_t)krow * 128 + e0];
                c = *(const float4*)&kp[base + (size_t)krow * 128 + e0 + 4];
            }
            int4 pkd = make_int4((int)pk2(a.x, a.y), (int)pk2(a.z, a.w),
                                 (int)pk2(c.x, c.y), (int)pk2(c.z, c.w));
            *(int4*)&KsU[(k * 128 + ((e0 * 2) ^ ((k & 7) << 4))) >> 1] = pkd;
        }
        // ---- stage V^T ----
        {
            const int k = tid & 31, e0 = (tid >> 5) * 8;
            const int vrow = jt + k;
            float4 a = make_float4(0.f, 0.f, 0.f, 0.f), c = a;
            if (vrow < 200) {
                a = *(const float4*)&vp[base + (size_t)vrow * 128 + e0];
                c = *(const float4*)&vp[base + (size_t)vrow * 128 + e0 + 4];
            }
            VtU[(e0 + 0) * 40 + k] = (ushort_t)f2bf(a.x);
            VtU[(e0 + 1) * 40 + k] = (ushort_t)f2bf(a.y);
            VtU[(e0 + 2) * 40 + k] = (ushort_t)f2bf(a.z);
            VtU[(e0 + 3) * 40 + k] = (ushort_t)f2bf(a.w);
            VtU[(e0 + 4) * 40 + k] = (ushort_t)f2bf(c.x);
            VtU[(e0 + 5) * 40 + k] = (ushort_t)f2bf(c.y);
            VtU[(e0 + 6) * 40 + k] = (ushort_t)f2bf(c.z);
            VtU[(e0 + 7) * 40 + k] = (ushort_t)f2bf(c.w);
        }
        __syncthreads();
        if (!wactive) continue;

        // ---- QK^T (S^T layout): d0 keys jt+[0,16), d1 keys jt+[16,32) ----
        f32x4 d0 = {0.f, 0.f, 0.f, 0.f}, d1 = d0;
#pragma unroll
        for (int f = 0; f < 2; ++f) {
            const int ebyte = g4 * 16 + f * 64;
            const int sw = ebyte ^ ((q15 & 7) << 4);
            bf16x8 a0 = *(const bf16x8*)&KsU[(q15 * 128 + sw) >> 1];
            bf16x8 a1 = *(const bf16x8*)&KsU[((q15 + 16) * 128 + sw) >> 1];
            d0 = __builtin_amdgcn_mfma_f32_16x16x32_bf16(a0, qf[f], d0, 0, 0, 0);
            d1 = __builtin_amdgcn_mfma_f32_16x16x32_bf16(a1, qf[f], d1, 0, 0, 0);
        }
        // ---- online softmax (per q = lane&15; keys split over g4 and regs) ----
        const int kb = jt + g4 * 4;
        float p[8];
        float tmax = -1e30f;
#pragma unroll
        for (int r = 0; r < 4; ++r) {
            const float s0 = (kb + r      <= qglob) ? d0[r] * 0.125f : -1e30f;
            const float s1 = (kb + r + 16 <= qglob) ? d1[r] * 0.125f : -1e30f;
            p[r] = s0; p[r + 4] = s1;
            tmax = fmaxf(tmax, fmaxf(s0, s1));
        }
        tmax = fmaxf(tmax, __shfl_xor(tmax, 16, 64));
        tmax = fmaxf(tmax, __shfl_xor(tmax, 32, 64));
        const float mnew = fmaxf(mrun, tmax);
        const float corr = __expf(mrun - mnew);
        mrun = mnew;
        float tsum = 0.f;
#pragma unroll
        for (int i = 0; i < 8; ++i) {
            float pe = __expf(p[i] - mnew);
            pe = bf2f(f2bf(pe));           // match bf16 P used in PV
            p[i] = pe;
            tsum += pe;
        }
        tsum += __shfl_xor(tsum, 16, 64);
        tsum += __shfl_xor(tsum, 32, 64);
        lrun = lrun * corr + tsum;
        // ---- write P[q][k] (bf16 pairs), row stride 40 ----
        const int kl = g4 * 4;
        *(unsigned*)&PbW[q15 * 40 + kl]          = pk2(p[0], p[1]);
        *(unsigned*)&PbW[q15 * 40 + kl + 2]      = pk2(p[2], p[3]);
        *(unsigned*)&PbW[q15 * 40 + 16 + kl]     = pk2(p[4], p[5]);
        *(unsigned*)&PbW[q15 * 40 + 16 + kl + 2] = pk2(p[6], p[7]);
        asm volatile("" ::: "memory");
        // ---- rescale O (rows q = g4*4+r) ----
        float corr_r[4];
#pragma unroll
        for (int r = 0; r < 4; ++r) corr_r[r] = __shfl(corr, g4 * 4 + r, 64);
#pragma unroll
        for (int nt = 0; nt < 4; ++nt) {
#pragma unroll
            for (int r = 0; r < 4; ++r) Oacc[nt][r] *= corr_r[r];
        }
        // ---- PV: O[q][e] += P[q][k] @ Vt[e][k] ----
        bf16x8 pa = *(const bf16x8*)&PbW[q15 * 40 + g4 * 8];
#pragma unroll
        for (int nt = 0; nt < 4; ++nt) {
            bf16x8 vb = *(const bf16x8*)&VtU[(nt * 16 + q15) * 40 + g4 * 8];
            Oacc[nt] = __builtin_amdgcn_mfma_f32_16x16x32_bf16(pa, vb, Oacc[nt], 0, 0, 0);
        }
    }
    // ---- epilogue: O[q][e] / l ----
    if (wactive) {
        float linv[4];
#pragma unroll
        for (int r = 0; r < 4; ++r) linv[r] = 1.f / __shfl(lrun, g4 * 4 + r, 64);
#pragma unroll
        for (int r = 0; r < 4; ++r) {
            const int qg = qw + g4 * 4 + r;
            if (qg < 200) {
#pragma unroll
                for (int nt = 0; nt < 4; ++nt)
                    outp[base + (size_t)qg * 128 + nt * 16 + q15] = Oacc[nt][r] * linv[r];
            }
        }
    }
}

// ---------------------------------------------------------------------------
__global__ __launch_bounds__(256) void logits_kernel(const float* __restrict__ lf,
                                                     const float* __restrict__ G,
                                                     const float* __restrict__ negt,
                                                     const float* __restrict__ validL,
                                                     float* __restrict__ outp) {
    const int row = blockIdx.x * 4 + (threadIdx.x >> 6);
    const int lane = threadIdx.x & 63;
    if (row >= 25600) return;
    const int n = row / 200, j = row % 200;
    const float2 x  = *(const float2*)&lf[(size_t)row * 128 + lane * 2];
    const float2 g2 = *(const float2*)&G[((size_t)n * 201 + j + 1) * 128 + lane * 2];
    const float2 t2 = *(const float2*)&negt[(size_t)row * 128 + lane * 2];
    float sp = x.x * g2.x + x.y * g2.y;
    float sn = x.x * t2.x + x.y * t2.y;
#pragma unroll
    for (int m = 1; m < 64; m <<= 1) { sp += __shfl_xor(sp, m, 64); sn += __shfl_xor(sn, m, 64); }
    if (lane == 0) { outp[row] = sp * validL[row]; outp[25600 + row] = sn; }
}

// ---------------------------------------------------------------------------
extern "C" void kernel_launch(void* const* d_in, const int* in_sizes, int n_in,
                              void* d_out, int out_size, void* d_ws, size_t ws_size,
                              hipStream_t stream) {
    (void)in_sizes; (void)n_in; (void)out_size; (void)ws_size;
    const float* item_emb = (const float*)d_in[0];
    const float* pos_emb  = (const float*)d_in[1];
    const float* W_asp    = (const float*)d_in[2];
    const float* w_weight = (const float*)d_in[3];
    // d_in[4] w_bias: cancels in aspect softmax (shift invariance)
    const float* attn_g = (const float*)d_in[5];
    const float* attn_b = (const float*)d_in[6];
    const float* inW    = (const float*)d_in[7];
    const float* inB    = (const float*)d_in[8];
    const float* outW   = (const float*)d_in[9];
    const float* outB   = (const float*)d_in[10];
    const float* fwd_g  = (const float*)d_in[11];
    const float* fwd_b  = (const float*)d_in[12];
    const float* c1w    = (const float*)d_in[13];
    const float* c1b    = (const float*)d_in[14];
    const float* c2w    = (const float*)d_in[15];
    const float* c2b    = (const float*)d_in[16];
    const float* last_g = (const float*)d_in[17];
    const float* last_b = (const float*)d_in[18];
    const int* log_seqs = (const int*)d_in[20];
    const int* pos_seqs = (const int*)d_in[21];
    const int* neg_seqs = (const int*)d_in[22];

    float* ws = (float*)d_ws;
    const size_t S = (size_t)128 * 201 * 128;  // one (N, 201, 128) slot
    float* kvx   = ws;           float* qp = kvx;   // reuse after aspects<1>
    float* negx  = ws + S;       float* kp = negx;  // reuse after aspects<0>
    float* G     = ws + 2 * S;
    float* negt  = ws + 3 * S;
    float* seqs  = ws + 4 * S;
    float* Qn    = ws + 5 * S;
    float* vp    = ws + 6 * S;
    float* attno = ws + 7 * S;
    ushort_t* wb  = (ushort_t*)(ws + 8 * S);
    ushort_t* Wab  = wb;                    // 262144
    ushort_t* inWb = Wab + 262144;          // 98304
    ushort_t* outWb = inWb + 98304;         // 32768
    ushort_t* c1b_w = outWb + 32768;        // 32768
    ushort_t* c2b_w = c1b_w + 32768;        // 32768
    float* validE = ws + 8 * S + 229376;
    float* validL = validE + 128 * 201;
    float* pInd   = validL + 128 * 200;
    float* pCent  = pInd + 1608;
    float* outF   = (float*)d_out;

    const int M = 128 * 200;  // 25600

    cvt_bf16<<<dim3(1024), dim3(256), 0, stream>>>(W_asp, Wab, 262144);
    cvt_bf16<<<dim3(384),  dim3(256), 0, stream>>>(inW,  inWb, 98304);
    cvt_bf16<<<dim3(128),  dim3(256), 0, stream>>>(outW, outWb, 32768);
    cvt_bf16<<<dim3(128),  dim3(256), 0, stream>>>(c1w,  c1b_w, 32768);
    cvt_bf16<<<dim3(128),  dim3(256), 0, stream>>>(c2w,  c2b_w, 32768);
    gather_kernel<<<dim3(128 * 201 + 128 * 200), dim3(128), 0, stream>>>(
        item_emb, log_seqs, pos_seqs, neg_seqs, kvx, negx, validE, validL);
    aspects_kernel<1><<<dim3(1608), dim3(256), 0, stream>>>(
        kvx, Wab, w_weight, validE, G, pInd, pCent);
    aspects_kernel<0><<<dim3(1600), dim3(256), 0, stream>>>(
        negx, Wab, w_weight, validL, negt, nullptr, nullptr);
    reduce_kernel<<<dim3(1), dim3(256), 0, stream>>>(
        pInd, pCent, 1608, validE, 128 * 201, outF + 51200);
    seqs_init<<<dim3(12800), dim3(256), 0, stream>>>(G, pos_emb, validL, seqs);

    for (int i = 0; i < 2; ++i) {
        const ushort_t* Wq = inWb + (size_t)i * 384 * 128;
        const ushort_t* Wk = Wq + 128 * 128;
        const ushort_t* Wv = Wk + 128 * 128;
        const float* bq = inB + (size_t)i * 384;
        const float* bk = bq + 128;
        const float* bv = bk + 128;
        ln_kernel<<<dim3(6400), dim3(256), 0, stream>>>(seqs, attn_g + i * 128, attn_b + i * 128, Qn, M);
        mgemm<0><<<dim3(400), dim3(256), 0, stream>>>(Qn,   Wq, bq, nullptr, nullptr, qp);
        mgemm<0><<<dim3(400), dim3(256), 0, stream>>>(seqs, Wk, bk, nullptr, nullptr, kp);
        mgemm<0><<<dim3(400), dim3(256), 0, stream>>>(seqs, Wv, bv, nullptr, nullptr, vp);
        attn_kernel<<<dim3(1024), dim3(256), 0, stream>>>(qp, kp, vp, attno);
        mgemm<2><<<dim3(400), dim3(256), 0, stream>>>(
            attno, outWb + (size_t)i * 128 * 128, outB + i * 128, Qn, nullptr, seqs);
        ln_kernel<<<dim3(6400), dim3(256), 0, stream>>>(seqs, fwd_g + i * 128, fwd_b + i * 128, Qn, M);
        mgemm<1><<<dim3(400), dim3(256), 0, stream>>>(
            Qn, c1b_w + (size_t)i * 128 * 128, c1b + i * 128, nullptr, nullptr, qp);
        mgemm<3><<<dim3(400), dim3(256), 0, stream>>>(
            qp, c2b_w + (size_t)i * 128 * 128, c2b + i * 128, Qn, validL, seqs);
    }
    ln_kernel<<<dim3(6400), dim3(256), 0, stream>>>(seqs, last_g, last_b, Qn, M);
    logits_kernel<<<dim3(6400), dim3(256), 0, stream>>>(Qn, G, negt, validL, outF);
}

// Round 6
// 508.897 us; speedup vs baseline: 5.0225x; 1.0508x over previous
//
#include <hip/hip_runtime.h>
#include <cstddef>

// Problem constants: N=128, L=200, LE=201, E=128, A=16 aspects, NB=2, H=2, HD=64, TEMP=0.2
typedef __attribute__((ext_vector_type(8))) short bf16x8;
typedef __attribute__((ext_vector_type(4))) float f32x4;
typedef unsigned short ushort_t;

__device__ __forceinline__ short f2bf(float f) {
    unsigned u = __builtin_bit_cast(unsigned, f);
    u = (u + 0x7FFFu + ((u >> 16) & 1u)) >> 16;
    return (short)u;
}
__device__ __forceinline__ float bf2f(short s) {
    unsigned u = ((unsigned)(unsigned short)s) << 16;
    return __builtin_bit_cast(float, u);
}
__device__ __forceinline__ unsigned pk2(float a, float b) {
    return (unsigned)(unsigned short)f2bf(a) | ((unsigned)(unsigned short)f2bf(b) << 16);
}

// ---------------------------------------------------------------------------
__global__ void cvt_bf16(const float* __restrict__ src, ushort_t* __restrict__ dst, int n) {
    const int i = blockIdx.x * 256 + threadIdx.x;
    if (i < n) dst[i] = (ushort_t)f2bf(src[i]);
}

// ---------------------------------------------------------------------------
__global__ void gather_kernel(const float* __restrict__ item_emb,
                              const int* __restrict__ log_seqs,
                              const int* __restrict__ pos_seqs,
                              const int* __restrict__ neg_seqs,
                              float* __restrict__ kvx, float* __restrict__ negx,
                              float* __restrict__ validE, float* __restrict__ validL) {
    const int r = blockIdx.x;
    const int e = threadIdx.x;     // 128 threads
    const int NKV = 128 * 201;
    if (r < NKV) {
        const int n = r / 201, l = r % 201;
        float vl; int sidx;
        if (l < 200) { sidx = log_seqs[n * 200 + l]; vl = (sidx != 0) ? 1.f : 0.f; }
        else { vl = (log_seqs[n * 200 + 199] != 0) ? 1.f : 0.f; sidx = pos_seqs[n * 200 + 199]; }
        kvx[(size_t)r * 128 + e] = item_emb[(size_t)sidx * 128 + e] * vl;
        if (e == 0) validE[r] = vl;
    } else {
        const int rr = r - NKV;
        const int n = rr / 200, l = rr % 200;
        const float vl = (log_seqs[n * 200 + l] != 0) ? 1.f : 0.f;
        const int sidx = neg_seqs[n * 200 + l];
        negx[(size_t)rr * 128 + e] = item_emb[(size_t)sidx * 128 + e] * vl;
        if (e == 0) validL[rr] = vl;
    }
}

// ---------------------------------------------------------------------------
// Fused aspects kernel v2 (operand-swapped). 16 rows/block, 4 waves.
// A = W fragment (m = o_local), B = x fragment (n = row). Lane (g4,nn) of the
// MFMA result holds r[row=nn][o = 16t + 4*g4 + reg] -> 4 consecutive o per
// lane: packed b64 rsb writes, b128 reads everywhere downstream.
// rsb layout: [row][a][o], row stride 2184 shorts, a stride 136.
__global__ __launch_bounds__(256, 2) void aspects2_kernel(
        const float* __restrict__ X, const ushort_t* __restrict__ Wab,
        const float* __restrict__ w_weight, const float* __restrict__ validf,
        float* __restrict__ Gout, float* __restrict__ pInd, float* __restrict__ pCent,
        int nLossBlocks) {
    __shared__ ushort_t rsb[16 * 2184];    // v = r + x, bf16
    __shared__ ushort_t xsb[16 * 136];     // x bf16
    __shared__ float wal[128];             // w_a
    __shared__ float s_red[256];           // nrm2 -> sg
    __shared__ float s_lg[256];            // raw logit -> gateW
    __shared__ float s_pos[256];           // pos_s*5
    __shared__ float vld[16];
    __shared__ float centw[16];
    __shared__ float miw[16];

    const int tid = threadIdx.x;
    const int row0 = blockIdx.x * 16;
    const bool losses = (int)blockIdx.x < nLossBlocks;
    const int lane = tid & 63, w = tid >> 6;
    const int g4 = lane >> 4, nn = lane & 15;

    // ---- stage x (bf16), w_a, valid ----
    {
        const int r = tid >> 4, c8 = (tid & 15) * 8;
        const float* px = &X[(size_t)(row0 + r) * 128 + c8];
        float4 a = *(const float4*)px, b = *(const float4*)(px + 4);
        bf16x8 v;
        v[0] = f2bf(a.x); v[1] = f2bf(a.y); v[2] = f2bf(a.z); v[3] = f2bf(a.w);
        v[4] = f2bf(b.x); v[5] = f2bf(b.y); v[6] = f2bf(b.z); v[7] = f2bf(b.w);
        *(bf16x8*)&xsb[r * 136 + c8] = v;
    }
    if (tid < 128) wal[tid] = w_weight[128 + tid];
    if (tid < 16) vld[tid] = validf[row0 + tid];
    __syncthreads();

    // B fragments (x): lane nn -> row nn, k = g4*8 + f*32 + j
    bf16x8 xf[4];
#pragma unroll
    for (int f = 0; f < 4; ++f)
        xf[f] = *(const bf16x8*)&xsb[nn * 136 + f * 32 + g4 * 8];

    // ---- GEMM phase: wave w -> aspects 4w..4w+3 ----
    for (int al = 0; al < 4; ++al) {
        const int a = w * 4 + al;
        float npacc = 0.f, lpacc = 0.f;
#pragma unroll
        for (int t = 0; t < 8; ++t) {
            f32x4 d = {0.f, 0.f, 0.f, 0.f};
#pragma unroll
            for (int f = 0; f < 4; ++f) {
                bf16x8 wf = *(const bf16x8*)&Wab[(size_t)(a * 128 + t * 16 + nn) * 128 + f * 32 + g4 * 8];
                d = __builtin_amdgcn_mfma_f32_16x16x32_bf16(wf, xf[f], d, 0, 0, 0);
            }
            const int o0 = t * 16 + g4 * 4;
            const bf16x8 xb = *(const bf16x8*)&xsb[nn * 136 + (o0 & ~7)];
            const int xs0 = o0 & 4;   // 0 or 4 within the 8-vec
            const float x0 = bf2f(xb[xs0]), x1 = bf2f(xb[xs0 + 1]);
            const float x2 = bf2f(xb[xs0 + 2]), x3 = bf2f(xb[xs0 + 3]);
            const float v0 = d[0] + x0, v1 = d[1] + x1;
            const float v2 = d[2] + x2, v3 = d[3] + x3;
            const float4 wv = *(const float4*)&wal[o0];
            npacc += v0 * v0 + v1 * v1 + v2 * v2 + v3 * v3;
            lpacc += v0 * wv.x + v1 * wv.y + v2 * wv.z + v3 * wv.w;
            *(int2*)&rsb[nn * 2184 + a * 136 + o0] = make_int2((int)pk2(v0, v1), (int)pk2(v2, v3));
        }
        npacc += __shfl_xor(npacc, 16, 64);
        npacc += __shfl_xor(npacc, 32, 64);
        lpacc += __shfl_xor(lpacc, 16, 64);
        lpacc += __shfl_xor(lpacc, 32, 64);
        if (lane < 16) { s_red[nn * 16 + a] = npacc; s_lg[nn * 16 + a] = lpacc; }
    }
    __syncthreads();

    // ---- per-(row,aspect) scalars + gate softmax (tid = row*16 + a) ----
    {
        const float nrm = sqrtf(s_red[tid]);
        const float inv1 = 1.f / (nrm + 1e-8f);
        const float n2 = nrm * inv1;
        const float sg = inv1 / (n2 + 1e-8f);
        const float ts = n2 / (n2 + 1e-8f);
        const float logit = s_lg[tid] * inv1;
        float mx = logit;
#pragma unroll
        for (int m = 1; m < 16; m <<= 1) mx = fmaxf(mx, __shfl_xor(mx, m, 16));
        const float e = __expf(logit - mx);
        float ssum = e;
#pragma unroll
        for (int m = 1; m < 16; m <<= 1) ssum += __shfl_xor(ssum, m, 16);
        s_red[tid] = sg;
        s_pos[tid] = ts * ts * 5.f;
        s_lg[tid] = (e / ssum + 0.0625f) * inv1;
    }
    __syncthreads();

    // ---- G phase: thread -> (row = tid>>4, o8 = (tid&15)*8) ----
    {
        const int row = tid >> 4, ol = tid & 15, o8 = ol * 8;
        float g[8] = {0.f, 0.f, 0.f, 0.f, 0.f, 0.f, 0.f, 0.f};
        float sr[8] = {0.f, 0.f, 0.f, 0.f, 0.f, 0.f, 0.f, 0.f};
#pragma unroll
        for (int a = 0; a < 16; ++a) {
            const bf16x8 vb = *(const bf16x8*)&rsb[row * 2184 + a * 136 + o8];
            const float gw = s_lg[row * 16 + a];
#pragma unroll
            for (int j = 0; j < 8; ++j) {
                const float v = bf2f(vb[j]);
                g[j] += v * gw;
                sr[j] += v;
            }
        }
        float* go = &Gout[(size_t)(row0 + row) * 128 + o8];
        *(float4*)go       = make_float4(g[0], g[1], g[2], g[3]);
        *(float4*)(go + 4) = make_float4(g[4], g[5], g[6], g[7]);
        if (losses) {
            const bf16x8 xb = *(const bf16x8*)&xsb[row * 136 + o8];
            float c = 0.f;
#pragma unroll
            for (int j = 0; j < 8; ++j) {
                const float dd = 2.f * bf2f(xb[j]) - sr[j] * 0.0625f;
                c += dd * dd;
            }
            c += __shfl_xor(c, 1, 64);
            c += __shfl_xor(c, 2, 64);
            c += __shfl_xor(c, 4, 64);
            c += __shfl_xor(c, 8, 64);
            if (ol == 0) centw[row] = sqrtf(c) * vld[row];
        }
    }

    // ---- gram / mi (losses only): wave w handles rows 4w..4w+3 ----
    if (losses) {
        for (int rl = 0; rl < 4; ++rl) {
            const int row = w * 4 + rl;
            f32x4 dd = {0.f, 0.f, 0.f, 0.f};
#pragma unroll
            for (int f = 0; f < 4; ++f) {
                bf16x8 fr = *(const bf16x8*)&rsb[row * 2184 + nn * 136 + f * 32 + g4 * 8];
                dd = __builtin_amdgcn_mfma_f32_16x16x32_bf16(fr, fr, dd, 0, 0, 0);
            }
            const float sgb = s_red[row * 16 + nn];
            float mis = 0.f;
#pragma unroll
            for (int r = 0; r < 4; ++r) {
                const int a = g4 * 4 + r;
                const float sga = s_red[row * 16 + a];
                float eb = __expf(5.f * dd[r] * sga * sgb);
#pragma unroll
                for (int m = 1; m < 16; m <<= 1) eb += __shfl_xor(eb, m, 16);
                mis += -(s_pos[row * 16 + a] - logf(eb));
            }
            mis += __shfl_xor(mis, 16, 64);
            mis += __shfl_xor(mis, 32, 64);
            if (lane == 0) miw[row] = mis * vld[row];
        }
        __syncthreads();
        if (tid == 0) {
            float si = 0.f, sc = 0.f;
#pragma unroll
            for (int r = 0; r < 16; ++r) { si += miw[r]; sc += centw[r]; }
            pInd[blockIdx.x] = si;
            pCent[blockIdx.x] = sc;
        }
    }
}

// ---------------------------------------------------------------------------
// MFMA GEMM: C[M x 128] = X[M x 128] @ Wb^T (+bias)(+res)(relu)(*mask)
template <int EPI>
__global__ __launch_bounds__(256) void mgemm(const float* __restrict__ X,
                                             const ushort_t* __restrict__ Wb,
                                             const float* __restrict__ bias,
                                             const float* __restrict__ res,
                                             const float* __restrict__ mask,
                                             float* __restrict__ C) {
    const int tid = threadIdx.x, lane = tid & 63, w = tid >> 6;
    const int q = lane >> 4, nn = lane & 15;
    const int m0 = blockIdx.x * 64 + w * 16;
    bf16x8 af[4];
    const float* xr = &X[(size_t)(m0 + nn) * 128];
#pragma unroll
    for (int f = 0; f < 4; ++f) {
        const float* px = &xr[f * 32 + q * 8];
        bf16x8 v;
#pragma unroll
        for (int j = 0; j < 8; ++j) v[j] = f2bf(px[j]);
        af[f] = v;
    }
    f32x4 acc[8];
#pragma unroll
    for (int t = 0; t < 8; ++t) acc[t] = (f32x4){0.f, 0.f, 0.f, 0.f};
#pragma unroll
    for (int t = 0; t < 8; ++t) {
#pragma unroll
        for (int f = 0; f < 4; ++f) {
            bf16x8 b = *(const bf16x8*)&Wb[(size_t)(t * 16 + nn) * 128 + f * 32 + q * 8];
            acc[t] = __builtin_amdgcn_mfma_f32_16x16x32_bf16(af[f], b, acc[t], 0, 0, 0);
        }
    }
    float mk[4];
    if (EPI == 3) {
#pragma unroll
        for (int r = 0; r < 4; ++r) mk[r] = mask[m0 + q * 4 + r];
    }
#pragma unroll
    for (int t = 0; t < 8; ++t) {
        const int n = t * 16 + nn;
        const float bi = bias[n];
#pragma unroll
        for (int r = 0; r < 4; ++r) {
            const int row = m0 + q * 4 + r;
            float v = acc[t][r] + bi;
            if (EPI >= 2) v += res[(size_t)row * 128 + n];
            if (EPI == 1) v = fmaxf(v, 0.f);
            if (EPI == 3) v *= mk[r];
            C[(size_t)row * 128 + n] = v;
        }
    }
}

// ---------------------------------------------------------------------------
__global__ void reduce_kernel(const float* __restrict__ pInd, const float* __restrict__ pCent,
                              int nblk, const float* __restrict__ validE, int nve,
                              float* __restrict__ outp) {
    __shared__ float a1[256], a2[256], a3[256];
    const int tid = threadIdx.x;
    float si = 0.f, sc = 0.f, nv = 0.f;
    for (int t = tid; t < nblk; t += 256) { si += pInd[t]; sc += pCent[t]; }
    for (int t = tid; t < nve; t += 256) nv += validE[t];
    a1[tid] = si; a2[tid] = sc; a3[tid] = nv;
    __syncthreads();
    for (int s = 128; s > 0; s >>= 1) {
        if (tid < s) { a1[tid] += a1[tid + s]; a2[tid] += a2[tid + s]; a3[tid] += a3[tid + s]; }
        __syncthreads();
    }
    if (tid == 0) { outp[0] = a1[0] / a3[0]; outp[1] = a2[0] / a3[0]; }
}

// ---------------------------------------------------------------------------
__global__ void seqs_init(const float* __restrict__ G, const float* __restrict__ pos_emb,
                          const float* __restrict__ validL, float* __restrict__ seqs) {
    const int idx = blockIdx.x * 256 + threadIdx.x;
    const int e = idx & 127;
    const int nl = idx >> 7;
    const int l = nl % 200, n = nl / 200;
    const float v = G[((size_t)n * 201 + l) * 128 + e] * 11.313708498984761f + pos_emb[l * 128 + e];
    seqs[idx] = v * validL[nl];
}

// ---------------------------------------------------------------------------
__global__ __launch_bounds__(256) void ln_kernel(const float* __restrict__ X,
                                                 const float* __restrict__ g,
                                                 const float* __restrict__ b,
                                                 float* __restrict__ Y, int M) {
    const int row = blockIdx.x * 4 + (threadIdx.x >> 6);
    const int lane = threadIdx.x & 63;
    if (row >= M) return;
    const float2 x = *(const float2*)&X[(size_t)row * 128 + lane * 2];
    float s = x.x + x.y, sq = x.x * x.x + x.y * x.y;
#pragma unroll
    for (int m = 1; m < 64; m <<= 1) { s += __shfl_xor(s, m, 64); sq += __shfl_xor(sq, m, 64); }
    const float mean = s * 0.0078125f;
    const float var = fmaxf(sq * 0.0078125f - mean * mean, 0.f);
    const float inv = rsqrtf(var + 1e-8f);
    const float2 gg = *(const float2*)&g[lane * 2];
    const float2 bb = *(const float2*)&b[lane * 2];
    float2 y;
    y.x = (x.x - mean) * inv * gg.x + bb.x;
    y.y = (x.y - mean) * inv * gg.y + bb.y;
    *(float2*)&Y[(size_t)row * 128 + lane * 2] = y;
}

// ---------------------------------------------------------------------------
// MFMA flash attention (as R5, passing). Grid = 256 (n,h) x 4 query-tiles.
__global__ __launch_bounds__(256) void attn_kernel(const float* __restrict__ qp,
                                                   const float* __restrict__ kp,
                                                   const float* __restrict__ vp,
                                                   float* __restrict__ outp) {
    __shared__ ushort_t KsU[2048];          // K tile 32x64 bf16, XOR-swizzled rows of 128B
    __shared__ ushort_t VtU[2560];          // V^T tile [e=64][k], row stride 40 ush
    __shared__ ushort_t Pb[2560];           // per-wave P [q=16][k=32], row stride 40 ush

    const int tid = threadIdx.x, lane = tid & 63, w = tid >> 6;
    const int b = blockIdx.x;
    const int nh = b >> 2, qt = b & 3;
    const int n = nh >> 1, h = nh & 1;
    const size_t base = (size_t)n * 200 * 128 + (size_t)h * 64;
    const int qw = qt * 64 + w * 16;        // wave's first query
    const bool wactive = qw < 200;
    const int q15 = lane & 15, g4 = lane >> 4;
    const int qglob = qw + q15;             // query this lane scores (S^T layout)

    bf16x8 qf[2];
    {
        const int qr = (qglob < 200) ? qglob : 199;
        const float* px = &qp[base + (size_t)qr * 128 + g4 * 8];
#pragma unroll
        for (int f = 0; f < 2; ++f) {
            bf16x8 v;
#pragma unroll
            for (int j = 0; j < 8; ++j) v[j] = f2bf(px[f * 32 + j]);
            qf[f] = v;
        }
    }
    f32x4 Oacc[4];
#pragma unroll
    for (int nt = 0; nt < 4; ++nt) Oacc[nt] = (f32x4){0.f, 0.f, 0.f, 0.f};
    float mrun = -1e30f, lrun = 0.f;

    const int kmax = min(200, qt * 64 + 64);
    ushort_t* PbW = Pb + w * 640;

    for (int jt = 0; jt < kmax; jt += 32) {
        __syncthreads();
        {
            const int k = tid >> 3, e0 = (tid & 7) * 8;
            const int krow = jt + k;
            float4 a = make_float4(0.f, 0.f, 0.f, 0.f), c = a;
            if (krow < 200) {
                a = *(const float4*)&kp[base + (size_t)krow * 128 + e0];
                c = *(const float4*)&kp[base + (size_t)krow * 128 + e0 + 4];
            }
            int4 pkd = make_int4((int)pk2(a.x, a.y), (int)pk2(a.z, a.w),
                                 (int)pk2(c.x, c.y), (int)pk2(c.z, c.w));
            *(int4*)&KsU[(k * 128 + ((e0 * 2) ^ ((k & 7) << 4))) >> 1] = pkd;
        }
        {
            const int k = tid & 31, e0 = (tid >> 5) * 8;
            const int vrow = jt + k;
            float4 a = make_float4(0.f, 0.f, 0.f, 0.f), c = a;
            if (vrow < 200) {
                a = *(const float4*)&vp[base + (size_t)vrow * 128 + e0];
                c = *(const float4*)&vp[base + (size_t)vrow * 128 + e0 + 4];
            }
            VtU[(e0 + 0) * 40 + k] = (ushort_t)f2bf(a.x);
            VtU[(e0 + 1) * 40 + k] = (ushort_t)f2bf(a.y);
            VtU[(e0 + 2) * 40 + k] = (ushort_t)f2bf(a.z);
            VtU[(e0 + 3) * 40 + k] = (ushort_t)f2bf(a.w);
            VtU[(e0 + 4) * 40 + k] = (ushort_t)f2bf(c.x);
            VtU[(e0 + 5) * 40 + k] = (ushort_t)f2bf(c.y);
            VtU[(e0 + 6) * 40 + k] = (ushort_t)f2bf(c.z);
            VtU[(e0 + 7) * 40 + k] = (ushort_t)f2bf(c.w);
        }
        __syncthreads();
        if (!wactive) continue;

        f32x4 d0 = {0.f, 0.f, 0.f, 0.f}, d1 = d0;
#pragma unroll
        for (int f = 0; f < 2; ++f) {
            const int ebyte = g4 * 16 + f * 64;
            const int sw = ebyte ^ ((q15 & 7) << 4);
            bf16x8 a0 = *(const bf16x8*)&KsU[(q15 * 128 + sw) >> 1];
            bf16x8 a1 = *(const bf16x8*)&KsU[((q15 + 16) * 128 + sw) >> 1];
            d0 = __builtin_amdgcn_mfma_f32_16x16x32_bf16(a0, qf[f], d0, 0, 0, 0);
            d1 = __builtin_amdgcn_mfma_f32_16x16x32_bf16(a1, qf[f], d1, 0, 0, 0);
        }
        const int kb = jt + g4 * 4;
        float p[8];
        float tmax = -1e30f;
#pragma unroll
        for (int r = 0; r < 4; ++r) {
            const float s0 = (kb + r      <= qglob) ? d0[r] * 0.125f : -1e30f;
            const float s1 = (kb + r + 16 <= qglob) ? d1[r] * 0.125f : -1e30f;
            p[r] = s0; p[r + 4] = s1;
            tmax = fmaxf(tmax, fmaxf(s0, s1));
        }
        tmax = fmaxf(tmax, __shfl_xor(tmax, 16, 64));
        tmax = fmaxf(tmax, __shfl_xor(tmax, 32, 64));
        const float mnew = fmaxf(mrun, tmax);
        const float corr = __expf(mrun - mnew);
        mrun = mnew;
        float tsum = 0.f;
#pragma unroll
        for (int i = 0; i < 8; ++i) {
            float pe = __expf(p[i] - mnew);
            pe = bf2f(f2bf(pe));
            p[i] = pe;
            tsum += pe;
        }
        tsum += __shfl_xor(tsum, 16, 64);
        tsum += __shfl_xor(tsum, 32, 64);
        lrun = lrun * corr + tsum;
        const int kl = g4 * 4;
        *(unsigned*)&PbW[q15 * 40 + kl]          = pk2(p[0], p[1]);
        *(unsigned*)&PbW[q15 * 40 + kl + 2]      = pk2(p[2], p[3]);
        *(unsigned*)&PbW[q15 * 40 + 16 + kl]     = pk2(p[4], p[5]);
        *(unsigned*)&PbW[q15 * 40 + 16 + kl + 2] = pk2(p[6], p[7]);
        asm volatile("" ::: "memory");
        float corr_r[4];
#pragma unroll
        for (int r = 0; r < 4; ++r) corr_r[r] = __shfl(corr, g4 * 4 + r, 64);
#pragma unroll
        for (int nt = 0; nt < 4; ++nt) {
#pragma unroll
            for (int r = 0; r < 4; ++r) Oacc[nt][r] *= corr_r[r];
        }
        bf16x8 pa = *(const bf16x8*)&PbW[q15 * 40 + g4 * 8];
#pragma unroll
        for (int nt = 0; nt < 4; ++nt) {
            bf16x8 vb = *(const bf16x8*)&VtU[(nt * 16 + q15) * 40 + g4 * 8];
            Oacc[nt] = __builtin_amdgcn_mfma_f32_16x16x32_bf16(pa, vb, Oacc[nt], 0, 0, 0);
        }
    }
    if (wactive) {
        float linv[4];
#pragma unroll
        for (int r = 0; r < 4; ++r) linv[r] = 1.f / __shfl(lrun, g4 * 4 + r, 64);
#pragma unroll
        for (int r = 0; r < 4; ++r) {
            const int qg = qw + g4 * 4 + r;
            if (qg < 200) {
#pragma unroll
                for (int nt = 0; nt < 4; ++nt)
                    outp[base + (size_t)qg * 128 + nt * 16 + q15] = Oacc[nt][r] * linv[r];
            }
        }
    }
}

// ---------------------------------------------------------------------------
__global__ __launch_bounds__(256) void logits_kernel(const float* __restrict__ lf,
                                                     const float* __restrict__ G,
                                                     const float* __restrict__ negt,
                                                     const float* __restrict__ validL,
                                                     float* __restrict__ outp) {
    const int row = blockIdx.x * 4 + (threadIdx.x >> 6);
    const int lane = threadIdx.x & 63;
    if (row >= 25600) return;
    const int n = row / 200, j = row % 200;
    const float2 x  = *(const float2*)&lf[(size_t)row * 128 + lane * 2];
    const float2 g2 = *(const float2*)&G[((size_t)n * 201 + j + 1) * 128 + lane * 2];
    const float2 t2 = *(const float2*)&negt[(size_t)row * 128 + lane * 2];
    float sp = x.x * g2.x + x.y * g2.y;
    float sn = x.x * t2.x + x.y * t2.y;
#pragma unroll
    for (int m = 1; m < 64; m <<= 1) { sp += __shfl_xor(sp, m, 64); sn += __shfl_xor(sn, m, 64); }
    if (lane == 0) { outp[row] = sp * validL[row]; outp[25600 + row] = sn; }
}

// ---------------------------------------------------------------------------
extern "C" void kernel_launch(void* const* d_in, const int* in_sizes, int n_in,
                              void* d_out, int out_size, void* d_ws, size_t ws_size,
                              hipStream_t stream) {
    (void)in_sizes; (void)n_in; (void)out_size; (void)ws_size;
    const float* item_emb = (const float*)d_in[0];
    const float* pos_emb  = (const float*)d_in[1];
    const float* W_asp    = (const float*)d_in[2];
    const float* w_weight = (const float*)d_in[3];
    // d_in[4] w_bias: cancels in aspect softmax (shift invariance)
    const float* attn_g = (const float*)d_in[5];
    const float* attn_b = (const float*)d_in[6];
    const float* inW    = (const float*)d_in[7];
    const float* inB    = (const float*)d_in[8];
    const float* outW   = (const float*)d_in[9];
    const float* outB   = (const float*)d_in[10];
    const float* fwd_g  = (const float*)d_in[11];
    const float* fwd_b  = (const float*)d_in[12];
    const float* c1w    = (const float*)d_in[13];
    const float* c1b    = (const float*)d_in[14];
    const float* c2w    = (const float*)d_in[15];
    const float* c2b    = (const float*)d_in[16];
    const float* last_g = (const float*)d_in[17];
    const float* last_b = (const float*)d_in[18];
    const int* log_seqs = (const int*)d_in[20];
    const int* pos_seqs = (const int*)d_in[21];
    const int* neg_seqs = (const int*)d_in[22];

    float* ws = (float*)d_ws;
    const size_t S = (size_t)128 * 201 * 128;  // one (N, 201, 128) slot
    float* kvx   = ws;           float* qp = kvx;   // kvx||negx contiguous rows
    float* negx  = ws + S;       float* kp = negx;
    float* G     = ws + 2 * S;                      // G||negt contiguous rows
    float* negt  = ws + 3 * S;
    float* seqs  = ws + 4 * S;
    float* Qn    = ws + 5 * S;
    float* vp    = ws + 6 * S;
    float* attno = ws + 7 * S;
    ushort_t* wb  = (ushort_t*)(ws + 8 * S);
    ushort_t* Wab  = wb;                    // 262144
    ushort_t* inWb = Wab + 262144;          // 98304
    ushort_t* outWb = inWb + 98304;         // 32768
    ushort_t* c1b_w = outWb + 32768;        // 32768
    ushort_t* c2b_w = c1b_w + 32768;        // 32768
    float* validE = ws + 8 * S + 229376;    // validE||validL contiguous
    float* validL = validE + 128 * 201;
    float* pInd   = validL + 128 * 200;
    float* pCent  = pInd + 1608;
    float* outF   = (float*)d_out;

    const int M = 128 * 200;  // 25600

    cvt_bf16<<<dim3(1024), dim3(256), 0, stream>>>(W_asp, Wab, 262144);
    cvt_bf16<<<dim3(384),  dim3(256), 0, stream>>>(inW,  inWb, 98304);
    cvt_bf16<<<dim3(128),  dim3(256), 0, stream>>>(outW, outWb, 32768);
    cvt_bf16<<<dim3(128),  dim3(256), 0, stream>>>(c1w,  c1b_w, 32768);
    cvt_bf16<<<dim3(128),  dim3(256), 0, stream>>>(c2w,  c2b_w, 32768);
    gather_kernel<<<dim3(128 * 201 + 128 * 200), dim3(128), 0, stream>>>(
        item_emb, log_seqs, pos_seqs, neg_seqs, kvx, negx, validE, validL);
    // merged: rows 0..25727 = kv (losses), rows 25728..51327 = neg
    aspects2_kernel<<<dim3(3208), dim3(256), 0, stream>>>(
        kvx, Wab, w_weight, validE, G, pInd, pCent, 1608);
    reduce_kernel<<<dim3(1), dim3(256), 0, stream>>>(
        pInd, pCent, 1608, validE, 128 * 201, outF + 51200);
    seqs_init<<<dim3(12800), dim3(256), 0, stream>>>(G, pos_emb, validL, seqs);

    for (int i = 0; i < 2; ++i) {
        const ushort_t* Wq = inWb + (size_t)i * 384 * 128;
        const ushort_t* Wk = Wq + 128 * 128;
        const ushort_t* Wv = Wk + 128 * 128;
        const float* bq = inB + (size_t)i * 384;
        const float* bk = bq + 128;
        const float* bv = bk + 128;
        ln_kernel<<<dim3(6400), dim3(256), 0, stream>>>(seqs, attn_g + i * 128, attn_b + i * 128, Qn, M);
        mgemm<0><<<dim3(400), dim3(256), 0, stream>>>(Qn,   Wq, bq, nullptr, nullptr, qp);
        mgemm<0><<<dim3(400), dim3(256), 0, stream>>>(seqs, Wk, bk, nullptr, nullptr, kp);
        mgemm<0><<<dim3(400), dim3(256), 0, stream>>>(seqs, Wv, bv, nullptr, nullptr, vp);
        attn_kernel<<<dim3(1024), dim3(256), 0, stream>>>(qp, kp, vp, attno);
        mgemm<2><<<dim3(400), dim3(256), 0, stream>>>(
            attno, outWb + (size_t)i * 128 * 128, outB + i * 128, Qn, nullptr, seqs);
        ln_kernel<<<dim3(6400), dim3(256), 0, stream>>>(seqs, fwd_g + i * 128, fwd_b + i * 128, Qn, M);
        mgemm<1><<<dim3(400), dim3(256), 0, stream>>>(
            Qn, c1b_w + (size_t)i * 128 * 128, c1b + i * 128, nullptr, nullptr, qp);
        mgemm<3><<<dim3(400), dim3(256), 0, stream>>>(
            qp, c2b_w + (size_t)i * 128 * 128, c2b + i * 128, Qn, validL, seqs);
    }
    ln_kernel<<<dim3(6400), dim3(256), 0, stream>>>(seqs, last_g, last_b, Qn, M);
    logits_kernel<<<dim3(6400), dim3(256), 0, stream>>>(Qn, G, negt, validL, outF);
}